// Round 1
// baseline (2621.590 us; speedup 1.0000x reference)
//
#include <hip/hip_runtime.h>
#include <math.h>
#include <stdint.h>

#define HIDDEN 640
#define NTOK   16384   // 32*512
#define LSEQ   512
#define BATCH  32
#define NQH    10
#define NKVH   2
#define HDIM   64
#define GROUPS 5

// ---------------------------------------------------------------------------
// int8 dot of 4 packed bytes. Written as sext-mul-add pattern so LLVM can
// pattern-match v_dot4_i32_i8 if the target supports it; guaranteed to compile
// regardless. (Round 2 TODO: try __builtin_amdgcn_sdot4 explicitly.)
__device__ __forceinline__ int dot4(int a, int b, int acc){
  int8_t a0=(int8_t)a, a1=(int8_t)(a>>8), a2=(int8_t)(a>>16), a3=(int8_t)(a>>24);
  int8_t b0=(int8_t)b, b1=(int8_t)(b>>8), b2=(int8_t)(b>>16), b3=(int8_t)(b>>24);
  return acc + a0*b0 + a1*b1 + a2*b2 + a3*b3;
}

// ---------------------------------------------------------------------------
// sum(|w|) -> atomicAdd into out (one float). Grid-stride.
__global__ __launch_bounds__(256) void absum_kernel(const float* __restrict__ w, int n,
                                                    float* __restrict__ out){
  __shared__ float red[256];
  int tid = threadIdx.x;
  float s = 0.f;
  for (int i = blockIdx.x*256 + tid; i < n; i += gridDim.x*256) s += fabsf(w[i]);
  red[tid] = s; __syncthreads();
  for (int off=128; off>0; off>>=1){ if (tid<off) red[tid]+=red[tid+off]; __syncthreads(); }
  if (tid==0) atomicAdd(out, red[0]);
}

// w_q = clip(round(w/alpha), -1, 1) as int8. alpha = max(mean|w|, 1e-10).
__global__ __launch_bounds__(256) void wquant_kernel(const float* __restrict__ w,
                                                     int8_t* __restrict__ wq, int n,
                                                     const float* __restrict__ sums, int idx,
                                                     float inv_n){
  float alpha = fmaxf(sums[idx]*inv_n, 1e-10f);
  float inva  = 1.0f/alpha;
  int i = blockIdx.x*256 + threadIdx.x;
  if (i < n){
    float t = rintf(w[i]*inva);            // rintf = round-half-even, matches jnp.round
    t = fminf(1.f, fmaxf(-1.f, t));
    wq[i] = (int8_t)t;
  }
}

// ---------------------------------------------------------------------------
__device__ __forceinline__ float breduce_sum(float v, float* red){
  int tid = threadIdx.x;
  __syncthreads();                // protect previous red users
  red[tid]=v; __syncthreads();
  #pragma unroll
  for (int off=128; off>0; off>>=1){ if (tid<off) red[tid]+=red[tid+off]; __syncthreads(); }
  return red[0];
}
__device__ __forceinline__ float breduce_max(float v, float* red){
  int tid = threadIdx.x;
  __syncthreads();
  red[tid]=v; __syncthreads();
  #pragma unroll
  for (int off=128; off>0; off>>=1){ if (tid<off) red[tid]=fmaxf(red[tid],red[tid+off]); __syncthreads(); }
  return red[0];
}

// quantize one gained-rmsnorm row held in LDS: val = h1[i]*inv2*g[i]
__device__ __forceinline__ void quant_one(const float* h1, float inv2,
    const float* __restrict__ g, int8_t* __restrict__ xq, float* __restrict__ gam,
    float* red, int m){
  int tid = threadIdx.x;
  float amax = 0.f;
  for (int i=tid;i<HIDDEN;i+=256){ float t = h1[i]*inv2*g[i]; amax = fmaxf(amax, fabsf(t)); }
  float gamma = fmaxf(breduce_max(amax, red), 1e-10f);
  float sc = 127.0f/gamma;
  for (int i=tid;i<HIDDEN;i+=256){
    float t = rintf(h1[i]*inv2*g[i]*sc);
    t = fminf(127.f, fmaxf(-128.f, t));
    xq[(size_t)m*HIDDEN + i] = (int8_t)t;
  }
  if (tid==0) gam[m] = gamma;
}

// per-token: h1 = rmsnorm(x, norm_w); then for q/k/v gains: rmsnorm(h1,g) -> int8 quant
__global__ __launch_bounds__(256) void token_prep_kernel(
    const float* __restrict__ x, const float* __restrict__ nw,
    const float* __restrict__ qg, const float* __restrict__ kg, const float* __restrict__ vg,
    int8_t* __restrict__ xqq, int8_t* __restrict__ xqk, int8_t* __restrict__ xqv,
    float* __restrict__ gq, float* __restrict__ gk, float* __restrict__ gv){
  __shared__ float h1[HIDDEN];
  __shared__ float red[256];
  int m = blockIdx.x, tid = threadIdx.x;
  const float* xr = x + (size_t)m*HIDDEN;
  float ss = 0.f;
  for (int i=tid;i<HIDDEN;i+=256){ float t = xr[i]; ss += t*t; }
  float rms1 = sqrtf(breduce_sum(ss, red)*(1.0f/HIDDEN) + 1e-6f);
  float inv1 = 1.0f/rms1;
  float ss2 = 0.f;
  for (int i=tid;i<HIDDEN;i+=256){ float t = xr[i]*inv1*nw[i]; h1[i]=t; ss2 += t*t; }
  float rms2 = sqrtf(breduce_sum(ss2, red)*(1.0f/HIDDEN) + 1e-6f);
  float inv2 = 1.0f/rms2;
  quant_one(h1, inv2, qg, xqq, gq, red, m);
  quant_one(h1, inv2, kg, xqk, gk, red, m);
  quant_one(h1, inv2, vg, xqv, gv, red, m);
}

// per-token prep for O projection: single rmsnorm(attn_out, o_g) -> quant
__global__ __launch_bounds__(256) void o_prep_kernel(const float* __restrict__ ao,
    const float* __restrict__ og, int8_t* __restrict__ xqo, float* __restrict__ go){
  __shared__ float h1[HIDDEN];
  __shared__ float red[256];
  int m = blockIdx.x, tid = threadIdx.x;
  const float* xr = ao + (size_t)m*HIDDEN;
  float ss = 0.f;
  for (int i=tid;i<HIDDEN;i+=256){ float t = xr[i]; h1[i]=t; ss += t*t; }
  float rms = sqrtf(breduce_sum(ss,red)*(1.0f/HIDDEN)+1e-6f);
  quant_one(h1, 1.0f/rms, og, xqo, go, red, m);
}

// ---------------------------------------------------------------------------
// QKV projection: one thread computes an even/odd output pair (rope pair).
// grid = (npairs/64, NTOK), block = 64. out layout [b][head][l][d].
__global__ __launch_bounds__(64) void qkv_gemm_kernel(
    const int8_t* __restrict__ xq, const float* __restrict__ gam,
    const int8_t* __restrict__ wq, const float* __restrict__ sums, int aidx, float inv_nw,
    float* __restrict__ outbuf, int nheads, int dorope){
  int m = blockIdx.y;
  int p = blockIdx.x*64 + threadIdx.x;
  int n0 = p<<1;
  const int8_t* xrow = xq + (size_t)m*HIDDEN;
  const int8_t* w0   = wq + (size_t)n0*HIDDEN;
  int acc0=0, acc1=0;
  #pragma unroll 8
  for (int kk=0; kk<HIDDEN; kk+=4){
    int a = *(const int*)(xrow+kk);
    acc0 = dot4(a, *(const int*)(w0+kk),        acc0);
    acc1 = dot4(a, *(const int*)(w0+HIDDEN+kk), acc1);
  }
  float alpha = fmaxf(sums[aidx]*inv_nw, 1e-10f);
  float sc = alpha*gam[m]*(1.0f/127.0f);
  float v0 = acc0*sc, v1 = acc1*sc;
  int b = m >> 9, l = m & 511;
  int head = n0 >> 6, d0 = n0 & 63;
  if (dorope){
    // freq = THETA^(-d0/64); ln(500000)=13.122363377404328
    float fr = __expf(-(float)d0*(1.0f/64.0f)*13.122363377404328f);
    float ang = (float)l * fr;
    float sn, cs;
    __sincosf(ang, &sn, &cs);
    float t0 = v0*cs - v1*sn;
    float t1 = v1*cs + v0*sn;
    v0=t0; v1=t1;
  }
  float* dst = outbuf + ((((size_t)b*nheads + head)*LSEQ + l)<<6) + d0;
  dst[0]=v0; dst[1]=v1;
}

// ---------------------------------------------------------------------------
// Flash attention, fp32. Block = 256 threads handles one (b, h, 64-row q tile).
// thread -> row r = tid/4, column-group cg = tid%3..  (cg = tid&3).
// S columns per thread: c = 4*cc + cg (interleaved -> conflict-free f4 reads).
// O columns per thread: d = cg*16 + 0..15 (contiguous -> coalesced f4 stores).
__global__ __launch_bounds__(256) void attn_kernel(
    const float* __restrict__ q, const float* __restrict__ k,
    const float* __restrict__ v, float* __restrict__ o){
  __shared__ float Ks[64][68];
  __shared__ float Vs[64][68];
  __shared__ float Ps[64][68];
  int tid = threadIdx.x;
  int qt = blockIdx.x, h = blockIdx.y, b = blockIdx.z;
  int hk = h / GROUPS;
  int r = tid >> 2, cg = tid & 3;
  int qrow = (qt<<6) + r;

  const float4* qp = (const float4*)(q + ((((size_t)b*NQH + h)*LSEQ) + qrow)*HDIM);
  float4 qreg[16];
  #pragma unroll
  for (int j=0;j<16;j++){
    float4 t = qp[j];
    t.x*=0.125f; t.y*=0.125f; t.z*=0.125f; t.w*=0.125f;   // fold in 1/sqrt(HD)
    qreg[j]=t;
  }
  const float4* kb = (const float4*)(k + (((size_t)b*NKVH + hk)*LSEQ)*HDIM);
  const float4* vb = (const float4*)(v + (((size_t)b*NKVH + hk)*LSEQ)*HDIM);

  float4 o0={0,0,0,0}, o1=o0, o2=o0, o3=o0;
  float mrow = -INFINITY, lrow = 0.f;

  for (int kt=0; kt<8; kt++){
    __syncthreads();
    #pragma unroll
    for (int i0=0;i0<4;i0++){
      int i = (i0<<8) + tid;
      int row = i>>4, col = (i&15)<<2;
      float4 t = kb[(kt<<10)+i];
      *(float4*)&Ks[row][col] = t;
      t = vb[(kt<<10)+i];
      *(float4*)&Vs[row][col] = t;
    }
    __syncthreads();

    // S = Q K^T for my 16 columns
    float s[16];
    #pragma unroll
    for (int cc=0;cc<16;cc++) s[cc]=0.f;
    #pragma unroll
    for (int kk4=0;kk4<16;kk4++){
      float4 q4 = qreg[kk4];
      #pragma unroll
      for (int cc=0;cc<16;cc++){
        const float4 k4 = *(const float4*)&Ks[(cc<<2)+cg][kk4<<2];
        s[cc] = fmaf(q4.x,k4.x, fmaf(q4.y,k4.y, fmaf(q4.z,k4.z, fmaf(q4.w,k4.w, s[cc]))));
      }
    }
    // online softmax (4 lanes per row: shfl_xor 1,2)
    float mx = s[0];
    #pragma unroll
    for (int cc=1;cc<16;cc++) mx = fmaxf(mx,s[cc]);
    mx = fmaxf(mx, __shfl_xor(mx,1));
    mx = fmaxf(mx, __shfl_xor(mx,2));
    float mnew = fmaxf(mrow, mx);
    float af = __expf(mrow - mnew);        // first tile: exp(-inf)=0
    float psum = 0.f;
    #pragma unroll
    for (int cc=0;cc<16;cc++){
      float pp = __expf(s[cc]-mnew);
      Ps[r][(cc<<2)+cg] = pp;
      psum += pp;
    }
    psum += __shfl_xor(psum,1);
    psum += __shfl_xor(psum,2);
    lrow = lrow*af + psum;
    mrow = mnew;
    o0.x*=af;o0.y*=af;o0.z*=af;o0.w*=af;
    o1.x*=af;o1.y*=af;o1.z*=af;o1.w*=af;
    o2.x*=af;o2.y*=af;o2.z*=af;o2.w*=af;
    o3.x*=af;o3.y*=af;o3.z*=af;o3.w*=af;
    __syncthreads();

    // O += P V for my 16 dims
    int dbase = cg<<4;
    #pragma unroll 16
    for (int kk=0;kk<64;kk++){
      float pp = Ps[r][kk];
      float4 v4;
      v4 = *(const float4*)&Vs[kk][dbase];
      o0.x=fmaf(pp,v4.x,o0.x); o0.y=fmaf(pp,v4.y,o0.y); o0.z=fmaf(pp,v4.z,o0.z); o0.w=fmaf(pp,v4.w,o0.w);
      v4 = *(const float4*)&Vs[kk][dbase+4];
      o1.x=fmaf(pp,v4.x,o1.x); o1.y=fmaf(pp,v4.y,o1.y); o1.z=fmaf(pp,v4.z,o1.z); o1.w=fmaf(pp,v4.w,o1.w);
      v4 = *(const float4*)&Vs[kk][dbase+8];
      o2.x=fmaf(pp,v4.x,o2.x); o2.y=fmaf(pp,v4.y,o2.y); o2.z=fmaf(pp,v4.z,o2.z); o2.w=fmaf(pp,v4.w,o2.w);
      v4 = *(const float4*)&Vs[kk][dbase+12];
      o3.x=fmaf(pp,v4.x,o3.x); o3.y=fmaf(pp,v4.y,o3.y); o3.z=fmaf(pp,v4.z,o3.z); o3.w=fmaf(pp,v4.w,o3.w);
    }
  }
  float invl = 1.0f/lrow;
  float* dst = o + ((size_t)((b<<9) + qrow))*HIDDEN + (h<<6) + (cg<<4);
  float4 w;
  w.x=o0.x*invl; w.y=o0.y*invl; w.z=o0.z*invl; w.w=o0.w*invl; ((float4*)dst)[0]=w;
  w.x=o1.x*invl; w.y=o1.y*invl; w.z=o1.z*invl; w.w=o1.w*invl; ((float4*)(dst+4))[0]=w;
  w.x=o2.x*invl; w.y=o2.y*invl; w.z=o2.z*invl; w.w=o2.w*invl; ((float4*)(dst+8))[0]=w;
  w.x=o3.x*invl; w.y=o3.y*invl; w.z=o3.z*invl; w.w=o3.w*invl; ((float4*)(dst+12))[0]=w;
}

// ---------------------------------------------------------------------------
// final: out[m][n] = dot(xq_o[m], wq_o[n]) * alpha*gamma/127 + residual
__global__ __launch_bounds__(64) void out_gemm_kernel(
    const int8_t* __restrict__ xq, const float* __restrict__ gam,
    const int8_t* __restrict__ wq, const float* __restrict__ sums, int aidx, float inv_nw,
    const float* __restrict__ resid, float* __restrict__ out){
  int m = blockIdx.y;
  int n = blockIdx.x*64 + threadIdx.x;
  const int8_t* xrow = xq + (size_t)m*HIDDEN;
  const int8_t* wrow = wq + (size_t)n*HIDDEN;
  int acc=0;
  #pragma unroll 8
  for (int kk=0;kk<HIDDEN;kk+=4)
    acc = dot4(*(const int*)(xrow+kk), *(const int*)(wrow+kk), acc);
  float alpha = fmaxf(sums[aidx]*inv_nw, 1e-10f);
  float sc = alpha*gam[m]*(1.0f/127.0f);
  size_t ofs = (size_t)m*HIDDEN + n;
  out[ofs] = acc*sc + resid[ofs];
}

// ---------------------------------------------------------------------------
extern "C" void kernel_launch(void* const* d_in, const int* in_sizes, int n_in,
                              void* d_out, int out_size, void* d_ws, size_t ws_size,
                              hipStream_t stream){
  (void)in_sizes; (void)n_in; (void)out_size; (void)ws_size;
  const float* x  = (const float*)d_in[0];
  const float* nw = (const float*)d_in[1];
  const float* qw = (const float*)d_in[2];
  const float* qg = (const float*)d_in[3];
  const float* kw = (const float*)d_in[4];
  const float* kg = (const float*)d_in[5];
  const float* vw = (const float*)d_in[6];
  const float* vg = (const float*)d_in[7];
  const float* ow = (const float*)d_in[8];
  const float* og = (const float*)d_in[9];
  float* out = (float*)d_out;

  char* base = (char*)d_ws;
  size_t off = 0;
  auto alloc = [&](size_t nbytes)->void*{
    off = (off + 255) & ~(size_t)255;
    void* p = base + off;
    off += nbytes;
    return p;
  };
  float*  sums = (float*) alloc(4*sizeof(float));
  int8_t* wq_q = (int8_t*)alloc(640*640);
  int8_t* wq_k = (int8_t*)alloc(128*640);
  int8_t* wq_v = (int8_t*)alloc(128*640);
  int8_t* wq_o = (int8_t*)alloc(640*640);
  int8_t* xq_q = (int8_t*)alloc((size_t)NTOK*HIDDEN);
  int8_t* xq_k = (int8_t*)alloc((size_t)NTOK*HIDDEN);
  int8_t* xq_v = (int8_t*)alloc((size_t)NTOK*HIDDEN);
  int8_t* xq_o = (int8_t*)alloc((size_t)NTOK*HIDDEN);
  float*  g_q  = (float*) alloc((size_t)NTOK*4);
  float*  g_k  = (float*) alloc((size_t)NTOK*4);
  float*  g_v  = (float*) alloc((size_t)NTOK*4);
  float*  g_o  = (float*) alloc((size_t)NTOK*4);
  float*  qbuf = (float*) alloc((size_t)BATCH*NQH *LSEQ*HDIM*4);
  float*  kbuf = (float*) alloc((size_t)BATCH*NKVH*LSEQ*HDIM*4);
  float*  vbuf = (float*) alloc((size_t)BATCH*NKVH*LSEQ*HDIM*4);
  float*  abuf = (float*) alloc((size_t)NTOK*HIDDEN*4);

  hipMemsetAsync(sums, 0, 4*sizeof(float), stream);
  absum_kernel<<<256,256,0,stream>>>(qw, 640*640, sums+0);
  absum_kernel<<<256,256,0,stream>>>(kw, 128*640, sums+1);
  absum_kernel<<<256,256,0,stream>>>(vw, 128*640, sums+2);
  absum_kernel<<<256,256,0,stream>>>(ow, 640*640, sums+3);
  wquant_kernel<<<(640*640+255)/256,256,0,stream>>>(qw, wq_q, 640*640, sums, 0, 1.0f/(640.f*640.f));
  wquant_kernel<<<(128*640+255)/256,256,0,stream>>>(kw, wq_k, 128*640, sums, 1, 1.0f/(128.f*640.f));
  wquant_kernel<<<(128*640+255)/256,256,0,stream>>>(vw, wq_v, 128*640, sums, 2, 1.0f/(128.f*640.f));
  wquant_kernel<<<(640*640+255)/256,256,0,stream>>>(ow, wq_o, 640*640, sums, 3, 1.0f/(640.f*640.f));

  token_prep_kernel<<<NTOK,256,0,stream>>>(x, nw, qg, kg, vg, xq_q, xq_k, xq_v, g_q, g_k, g_v);

  qkv_gemm_kernel<<<dim3(5,NTOK),64,0,stream>>>(xq_q, g_q, wq_q, sums, 0, 1.0f/(640.f*640.f), qbuf, NQH, 1);
  qkv_gemm_kernel<<<dim3(1,NTOK),64,0,stream>>>(xq_k, g_k, wq_k, sums, 1, 1.0f/(128.f*640.f), kbuf, NKVH, 1);
  qkv_gemm_kernel<<<dim3(1,NTOK),64,0,stream>>>(xq_v, g_v, wq_v, sums, 2, 1.0f/(128.f*640.f), vbuf, NKVH, 0);

  attn_kernel<<<dim3(8,NQH,BATCH),256,0,stream>>>(qbuf, kbuf, vbuf, abuf);

  o_prep_kernel<<<NTOK,256,0,stream>>>(abuf, og, xq_o, g_o);
  out_gemm_kernel<<<dim3(10,NTOK),64,0,stream>>>(xq_o, g_o, wq_o, sums, 3, 1.0f/(640.f*640.f), x, out);
}

// Round 3
// 1041.445 us; speedup vs baseline: 2.5173x; 2.5173x over previous
//
#include <hip/hip_runtime.h>
#include <math.h>
#include <stdint.h>

#define HIDDEN 640
#define NTOK   16384   // 32*512
#define LSEQ   512
#define BATCH  32
#define NQH    10
#define NKVH   2
#define HDIM   64
#define GROUPS 5

typedef int   int4v  __attribute__((ext_vector_type(4)));
typedef int   int16v __attribute__((ext_vector_type(16)));

// ---------------------------------------------------------------------------
// sum(|w|) -> atomicAdd into out (one float). Grid-stride.
__global__ __launch_bounds__(256) void absum_kernel(const float* __restrict__ w, int n,
                                                    float* __restrict__ out){
  __shared__ float red[256];
  int tid = threadIdx.x;
  float s = 0.f;
  for (int i = blockIdx.x*256 + tid; i < n; i += gridDim.x*256) s += fabsf(w[i]);
  red[tid] = s; __syncthreads();
  for (int off=128; off>0; off>>=1){ if (tid<off) red[tid]+=red[tid+off]; __syncthreads(); }
  if (tid==0) atomicAdd(out, red[0]);
}

// w_q = clip(round(w/alpha), -1, 1) as int8. alpha = max(mean|w|, 1e-10).
__global__ __launch_bounds__(256) void wquant_kernel(const float* __restrict__ w,
                                                     int8_t* __restrict__ wq, int n,
                                                     const float* __restrict__ sums, int idx,
                                                     float inv_n){
  float alpha = fmaxf(sums[idx]*inv_n, 1e-10f);
  float inva  = 1.0f/alpha;
  int i = blockIdx.x*256 + threadIdx.x;
  if (i < n){
    float t = rintf(w[i]*inva);            // rintf = round-half-even, matches jnp.round
    t = fminf(1.f, fmaxf(-1.f, t));
    wq[i] = (int8_t)t;
  }
}

// ---------------------------------------------------------------------------
__device__ __forceinline__ float breduce_sum(float v, float* red){
  int tid = threadIdx.x;
  __syncthreads();
  red[tid]=v; __syncthreads();
  #pragma unroll
  for (int off=128; off>0; off>>=1){ if (tid<off) red[tid]+=red[tid+off]; __syncthreads(); }
  return red[0];
}
__device__ __forceinline__ float breduce_max(float v, float* red){
  int tid = threadIdx.x;
  __syncthreads();
  red[tid]=v; __syncthreads();
  #pragma unroll
  for (int off=128; off>0; off>>=1){ if (tid<off) red[tid]=fmaxf(red[tid],red[tid+off]); __syncthreads(); }
  return red[0];
}

__device__ __forceinline__ void quant_one(const float* h1, float inv2,
    const float* __restrict__ g, int8_t* __restrict__ xq, float* __restrict__ gam,
    float* red, int m){
  int tid = threadIdx.x;
  float amax = 0.f;
  for (int i=tid;i<HIDDEN;i+=256){ float t = h1[i]*inv2*g[i]; amax = fmaxf(amax, fabsf(t)); }
  float gamma = fmaxf(breduce_max(amax, red), 1e-10f);
  float sc = 127.0f/gamma;
  for (int i=tid;i<HIDDEN;i+=256){
    float t = rintf(h1[i]*inv2*g[i]*sc);
    t = fminf(127.f, fmaxf(-128.f, t));
    xq[(size_t)m*HIDDEN + i] = (int8_t)t;
  }
  if (tid==0) gam[m] = gamma;
}

__global__ __launch_bounds__(256) void token_prep_kernel(
    const float* __restrict__ x, const float* __restrict__ nw,
    const float* __restrict__ qg, const float* __restrict__ kg, const float* __restrict__ vg,
    int8_t* __restrict__ xqq, int8_t* __restrict__ xqk, int8_t* __restrict__ xqv,
    float* __restrict__ gq, float* __restrict__ gk, float* __restrict__ gv){
  __shared__ float h1[HIDDEN];
  __shared__ float red[256];
  int m = blockIdx.x, tid = threadIdx.x;
  const float* xr = x + (size_t)m*HIDDEN;
  float ss = 0.f;
  for (int i=tid;i<HIDDEN;i+=256){ float t = xr[i]; ss += t*t; }
  float rms1 = sqrtf(breduce_sum(ss, red)*(1.0f/HIDDEN) + 1e-6f);
  float inv1 = 1.0f/rms1;
  float ss2 = 0.f;
  for (int i=tid;i<HIDDEN;i+=256){ float t = xr[i]*inv1*nw[i]; h1[i]=t; ss2 += t*t; }
  float rms2 = sqrtf(breduce_sum(ss2, red)*(1.0f/HIDDEN) + 1e-6f);
  float inv2 = 1.0f/rms2;
  quant_one(h1, inv2, qg, xqq, gq, red, m);
  quant_one(h1, inv2, kg, xqk, gk, red, m);
  quant_one(h1, inv2, vg, xqv, gv, red, m);
}

__global__ __launch_bounds__(256) void o_prep_kernel(const float* __restrict__ ao,
    const float* __restrict__ og, int8_t* __restrict__ xqo, float* __restrict__ go){
  __shared__ float h1[HIDDEN];
  __shared__ float red[256];
  int m = blockIdx.x, tid = threadIdx.x;
  const float* xr = ao + (size_t)m*HIDDEN;
  float ss = 0.f;
  for (int i=tid;i<HIDDEN;i+=256){ float t = xr[i]; h1[i]=t; ss += t*t; }
  float rms = sqrtf(breduce_sum(ss,red)*(1.0f/HIDDEN)+1e-6f);
  quant_one(h1, 1.0f/rms, og, xqo, go, red, m);
}

// ---------------------------------------------------------------------------
// MFMA i8 GEMM: block = 256 thr (4 waves). Wave w computes rows
// [m0+32w, m0+32w+32) x cols [n0, n0+64) via two v_mfma_i32_32x32x32_i8 accs.
// A frag: m=lane&31, k=(lane>>5)*16+j (16 bytes/lane, dwordx4 from row-major K).
// B frag: n=lane&31, k same split (wq is [N][K] row-major, so identical addressing).
// C/D:    col=lane&31, row=(reg&3)+8*(reg>>2)+4*(lane>>5)  [m74/m101 verified].
// mode 0: out[m*640+n] = val + resid          (O projection)
// mode 1: rope, out[b][head][l][d]            (Q/K)
// mode 2: no rope, out[b][head][l][d]         (V)
__global__ __launch_bounds__(256) void mfma_gemm_kernel(
    const int8_t* __restrict__ xq, const float* __restrict__ gam,
    const int8_t* __restrict__ wq,
    const float* __restrict__ sums, int aidx, float inv_nw,
    const float* __restrict__ resid, float* __restrict__ out,
    int nheads, int mode){
  int lane = threadIdx.x & 63;
  int w    = threadIdx.x >> 6;
  int m0   = blockIdx.y*128 + w*32;
  int n0   = blockIdx.x*64;
  int half = lane >> 5;
  int lan5 = lane & 31;

  const int8_t* arow = xq + (size_t)(m0 + lan5)*HIDDEN + half*16;
  const int8_t* brow0 = wq + (size_t)(n0      + lan5)*HIDDEN + half*16;
  const int8_t* brow1 = wq + (size_t)(n0 + 32 + lan5)*HIDDEN + half*16;

  int16v acc0 = {0}, acc1 = {0};
  #pragma unroll
  for (int kk=0; kk<HIDDEN; kk+=32){
    int4v a  = *(const int4v*)(arow  + kk);
    int4v b0 = *(const int4v*)(brow0 + kk);
    int4v b1 = *(const int4v*)(brow1 + kk);
    acc0 = __builtin_amdgcn_mfma_i32_32x32x32_i8(a, b0, acc0, 0, 0, 0);
    acc1 = __builtin_amdgcn_mfma_i32_32x32x32_i8(a, b1, acc1, 0, 0, 0);
  }

  float alpha = fmaxf(sums[aidx]*inv_nw, 1e-10f);
  // rope freqs per n-tile (d fixed per lane per tile)
  float fr0 = 0.f, fr1 = 0.f;
  if (mode == 1){
    int d0 = (lan5) & ~1;            // t=0: d = lan5
    int d1 = (32 + lan5) & ~1;       // t=1: d = 32+lan5
    fr0 = __expf(-(float)d0*(1.0f/64.0f)*13.122363377404328f);
    fr1 = __expf(-(float)d1*(1.0f/64.0f)*13.122363377404328f);
  }

  #pragma unroll
  for (int reg=0; reg<16; reg++){
    int m = m0 + (reg&3) + 8*(reg>>2) + 4*half;
    float sc = alpha*gam[m]*(1.0f/127.0f);
    float v0 = (float)acc0[reg]*sc;
    float v1 = (float)acc1[reg]*sc;
    if (mode == 0){
      size_t ofs = (size_t)m*HIDDEN;
      out[ofs + n0 + lan5]      = v0 + resid[ofs + n0 + lan5];
      out[ofs + n0 + 32 + lan5] = v1 + resid[ofs + n0 + 32 + lan5];
    } else {
      int b = m >> 9, l = m & 511;
      int head = n0 >> 6;                 // 64-col block == one head
      if (mode == 1){
        float p0 = __shfl_xor(v0, 1);
        float p1 = __shfl_xor(v1, 1);
        float sn0, cs0, sn1, cs1;
        __sincosf((float)l*fr0, &sn0, &cs0);
        __sincosf((float)l*fr1, &sn1, &cs1);
        if (lane & 1){ v0 = v0*cs0 + p0*sn0;  v1 = v1*cs1 + p1*sn1; }
        else         { v0 = v0*cs0 - p0*sn0;  v1 = v1*cs1 - p1*sn1; }
      }
      float* dst = out + ((((size_t)b*nheads + head)*LSEQ + l)<<6);
      dst[lan5]      = v0;
      dst[32 + lan5] = v1;
    }
  }
}

// ---------------------------------------------------------------------------
// Flash attention, fp32 (unchanged this round).
__global__ __launch_bounds__(256) void attn_kernel(
    const float* __restrict__ q, const float* __restrict__ k,
    const float* __restrict__ v, float* __restrict__ o){
  __shared__ float Ks[64][68];
  __shared__ float Vs[64][68];
  __shared__ float Ps[64][68];
  int tid = threadIdx.x;
  int qt = blockIdx.x, h = blockIdx.y, b = blockIdx.z;
  int hk = h / GROUPS;
  int r = tid >> 2, cg = tid & 3;
  int qrow = (qt<<6) + r;

  const float4* qp = (const float4*)(q + ((((size_t)b*NQH + h)*LSEQ) + qrow)*HDIM);
  float4 qreg[16];
  #pragma unroll
  for (int j=0;j<16;j++){
    float4 t = qp[j];
    t.x*=0.125f; t.y*=0.125f; t.z*=0.125f; t.w*=0.125f;
    qreg[j]=t;
  }
  const float4* kb = (const float4*)(k + (((size_t)b*NKVH + hk)*LSEQ)*HDIM);
  const float4* vb = (const float4*)(v + (((size_t)b*NKVH + hk)*LSEQ)*HDIM);

  float4 o0={0,0,0,0}, o1=o0, o2=o0, o3=o0;
  float mrow = -INFINITY, lrow = 0.f;

  for (int kt=0; kt<8; kt++){
    __syncthreads();
    #pragma unroll
    for (int i0=0;i0<4;i0++){
      int i = (i0<<8) + tid;
      int row = i>>4, col = (i&15)<<2;
      float4 t = kb[(kt<<10)+i];
      *(float4*)&Ks[row][col] = t;
      t = vb[(kt<<10)+i];
      *(float4*)&Vs[row][col] = t;
    }
    __syncthreads();

    float s[16];
    #pragma unroll
    for (int cc=0;cc<16;cc++) s[cc]=0.f;
    #pragma unroll
    for (int kk4=0;kk4<16;kk4++){
      float4 q4 = qreg[kk4];
      #pragma unroll
      for (int cc=0;cc<16;cc++){
        const float4 k4 = *(const float4*)&Ks[(cc<<2)+cg][kk4<<2];
        s[cc] = fmaf(q4.x,k4.x, fmaf(q4.y,k4.y, fmaf(q4.z,k4.z, fmaf(q4.w,k4.w, s[cc]))));
      }
    }
    float mx = s[0];
    #pragma unroll
    for (int cc=1;cc<16;cc++) mx = fmaxf(mx,s[cc]);
    mx = fmaxf(mx, __shfl_xor(mx,1));
    mx = fmaxf(mx, __shfl_xor(mx,2));
    float mnew = fmaxf(mrow, mx);
    float af = __expf(mrow - mnew);
    float psum = 0.f;
    #pragma unroll
    for (int cc=0;cc<16;cc++){
      float pp = __expf(s[cc]-mnew);
      Ps[r][(cc<<2)+cg] = pp;
      psum += pp;
    }
    psum += __shfl_xor(psum,1);
    psum += __shfl_xor(psum,2);
    lrow = lrow*af + psum;
    mrow = mnew;
    o0.x*=af;o0.y*=af;o0.z*=af;o0.w*=af;
    o1.x*=af;o1.y*=af;o1.z*=af;o1.w*=af;
    o2.x*=af;o2.y*=af;o2.z*=af;o2.w*=af;
    o3.x*=af;o3.y*=af;o3.z*=af;o3.w*=af;
    __syncthreads();

    int dbase = cg<<4;
    #pragma unroll 16
    for (int kk=0;kk<64;kk++){
      float pp = Ps[r][kk];
      float4 v4;
      v4 = *(const float4*)&Vs[kk][dbase];
      o0.x=fmaf(pp,v4.x,o0.x); o0.y=fmaf(pp,v4.y,o0.y); o0.z=fmaf(pp,v4.z,o0.z); o0.w=fmaf(pp,v4.w,o0.w);
      v4 = *(const float4*)&Vs[kk][dbase+4];
      o1.x=fmaf(pp,v4.x,o1.x); o1.y=fmaf(pp,v4.y,o1.y); o1.z=fmaf(pp,v4.z,o1.z); o1.w=fmaf(pp,v4.w,o1.w);
      v4 = *(const float4*)&Vs[kk][dbase+8];
      o2.x=fmaf(pp,v4.x,o2.x); o2.y=fmaf(pp,v4.y,o2.y); o2.z=fmaf(pp,v4.z,o2.z); o2.w=fmaf(pp,v4.w,o2.w);
      v4 = *(const float4*)&Vs[kk][dbase+12];
      o3.x=fmaf(pp,v4.x,o3.x); o3.y=fmaf(pp,v4.y,o3.y); o3.z=fmaf(pp,v4.z,o3.z); o3.w=fmaf(pp,v4.w,o3.w);
    }
  }
  float invl = 1.0f/lrow;
  float* dst = o + ((size_t)((b<<9) + qrow))*HIDDEN + (h<<6) + (cg<<4);
  float4 wv;
  wv.x=o0.x*invl; wv.y=o0.y*invl; wv.z=o0.z*invl; wv.w=o0.w*invl; ((float4*)dst)[0]=wv;
  wv.x=o1.x*invl; wv.y=o1.y*invl; wv.z=o1.z*invl; wv.w=o1.w*invl; ((float4*)(dst+4))[0]=wv;
  wv.x=o2.x*invl; wv.y=o2.y*invl; wv.z=o2.z*invl; wv.w=o2.w*invl; ((float4*)(dst+8))[0]=wv;
  wv.x=o3.x*invl; wv.y=o3.y*invl; wv.z=o3.z*invl; wv.w=o3.w*invl; ((float4*)(dst+12))[0]=wv;
}

// ---------------------------------------------------------------------------
extern "C" void kernel_launch(void* const* d_in, const int* in_sizes, int n_in,
                              void* d_out, int out_size, void* d_ws, size_t ws_size,
                              hipStream_t stream){
  (void)in_sizes; (void)n_in; (void)out_size; (void)ws_size;
  const float* x  = (const float*)d_in[0];
  const float* nw = (const float*)d_in[1];
  const float* qw = (const float*)d_in[2];
  const float* qg = (const float*)d_in[3];
  const float* kw = (const float*)d_in[4];
  const float* kg = (const float*)d_in[5];
  const float* vw = (const float*)d_in[6];
  const float* vg = (const float*)d_in[7];
  const float* ow = (const float*)d_in[8];
  const float* og = (const float*)d_in[9];
  float* out = (float*)d_out;

  char* base = (char*)d_ws;
  size_t off = 0;
  auto alloc = [&](size_t nbytes)->void*{
    off = (off + 255) & ~(size_t)255;
    void* p = base + off;
    off += nbytes;
    return p;
  };
  float*  sums = (float*) alloc(4*sizeof(float));
  int8_t* wq_q = (int8_t*)alloc(640*640);
  int8_t* wq_k = (int8_t*)alloc(128*640);
  int8_t* wq_v = (int8_t*)alloc(128*640);
  int8_t* wq_o = (int8_t*)alloc(640*640);
  int8_t* xq_q = (int8_t*)alloc((size_t)NTOK*HIDDEN);
  int8_t* xq_k = (int8_t*)alloc((size_t)NTOK*HIDDEN);
  int8_t* xq_v = (int8_t*)alloc((size_t)NTOK*HIDDEN);
  int8_t* xq_o = (int8_t*)alloc((size_t)NTOK*HIDDEN);
  float*  g_q  = (float*) alloc((size_t)NTOK*4);
  float*  g_k  = (float*) alloc((size_t)NTOK*4);
  float*  g_v  = (float*) alloc((size_t)NTOK*4);
  float*  g_o  = (float*) alloc((size_t)NTOK*4);
  float*  qbuf = (float*) alloc((size_t)BATCH*NQH *LSEQ*HDIM*4);
  float*  kbuf = (float*) alloc((size_t)BATCH*NKVH*LSEQ*HDIM*4);
  float*  vbuf = (float*) alloc((size_t)BATCH*NKVH*LSEQ*HDIM*4);
  float*  abuf = (float*) alloc((size_t)NTOK*HIDDEN*4);

  (void)hipMemsetAsync(sums, 0, 4*sizeof(float), stream);
  absum_kernel<<<256,256,0,stream>>>(qw, 640*640, sums+0);
  absum_kernel<<<256,256,0,stream>>>(kw, 128*640, sums+1);
  absum_kernel<<<256,256,0,stream>>>(vw, 128*640, sums+2);
  absum_kernel<<<256,256,0,stream>>>(ow, 640*640, sums+3);
  wquant_kernel<<<(640*640+255)/256,256,0,stream>>>(qw, wq_q, 640*640, sums, 0, 1.0f/(640.f*640.f));
  wquant_kernel<<<(128*640+255)/256,256,0,stream>>>(kw, wq_k, 128*640, sums, 1, 1.0f/(128.f*640.f));
  wquant_kernel<<<(128*640+255)/256,256,0,stream>>>(vw, wq_v, 128*640, sums, 2, 1.0f/(128.f*640.f));
  wquant_kernel<<<(640*640+255)/256,256,0,stream>>>(ow, wq_o, 640*640, sums, 3, 1.0f/(640.f*640.f));

  token_prep_kernel<<<NTOK,256,0,stream>>>(x, nw, qg, kg, vg, xq_q, xq_k, xq_v, g_q, g_k, g_v);

  // Q: M=16384, N=640 -> grid (10, 128); K: N=128 -> (2,128); V: N=128 -> (2,128)
  mfma_gemm_kernel<<<dim3(10,128),256,0,stream>>>(xq_q, g_q, wq_q, sums, 0, 1.0f/(640.f*640.f), nullptr, qbuf, NQH, 1);
  mfma_gemm_kernel<<<dim3(2,128),256,0,stream>>>(xq_k, g_k, wq_k, sums, 1, 1.0f/(128.f*640.f), nullptr, kbuf, NKVH, 1);
  mfma_gemm_kernel<<<dim3(2,128),256,0,stream>>>(xq_v, g_v, wq_v, sums, 2, 1.0f/(128.f*640.f), nullptr, vbuf, NKVH, 2);

  attn_kernel<<<dim3(8,NQH,BATCH),256,0,stream>>>(qbuf, kbuf, vbuf, abuf);

  o_prep_kernel<<<NTOK,256,0,stream>>>(abuf, og, xq_o, g_o);
  mfma_gemm_kernel<<<dim3(10,128),256,0,stream>>>(xq_o, g_o, wq_o, sums, 3, 1.0f/(640.f*640.f), x, out, 0, 0);
}

// Round 4
// 522.244 us; speedup vs baseline: 5.0199x; 1.9942x over previous
//
#include <hip/hip_runtime.h>
#include <math.h>
#include <stdint.h>

#define HIDDEN 640
#define NTOK   16384   // 32*512
#define LSEQ   512
#define BATCH  32
#define NQH    10
#define NKVH   2
#define HDIM   64
#define GROUPS 5

typedef int      int4v  __attribute__((ext_vector_type(4)));
typedef int      int16v __attribute__((ext_vector_type(16)));
typedef _Float16 f16x8  __attribute__((ext_vector_type(8)));
typedef float    f32x4  __attribute__((ext_vector_type(4)));

// ---------------------------------------------------------------------------
__global__ __launch_bounds__(256) void absum_kernel(const float* __restrict__ w, int n,
                                                    float* __restrict__ out){
  __shared__ float red[256];
  int tid = threadIdx.x;
  float s = 0.f;
  for (int i = blockIdx.x*256 + tid; i < n; i += gridDim.x*256) s += fabsf(w[i]);
  red[tid] = s; __syncthreads();
  for (int off=128; off>0; off>>=1){ if (tid<off) red[tid]+=red[tid+off]; __syncthreads(); }
  if (tid==0) atomicAdd(out, red[0]);
}

__global__ __launch_bounds__(256) void wquant_kernel(const float* __restrict__ w,
                                                     int8_t* __restrict__ wq, int n,
                                                     const float* __restrict__ sums, int idx,
                                                     float inv_n){
  float alpha = fmaxf(sums[idx]*inv_n, 1e-10f);
  float inva  = 1.0f/alpha;
  int i = blockIdx.x*256 + threadIdx.x;
  if (i < n){
    float t = rintf(w[i]*inva);
    t = fminf(1.f, fmaxf(-1.f, t));
    wq[i] = (int8_t)t;
  }
}

// ---------------------------------------------------------------------------
__device__ __forceinline__ float breduce_sum(float v, float* red){
  int tid = threadIdx.x;
  __syncthreads();
  red[tid]=v; __syncthreads();
  #pragma unroll
  for (int off=128; off>0; off>>=1){ if (tid<off) red[tid]+=red[tid+off]; __syncthreads(); }
  return red[0];
}
__device__ __forceinline__ float breduce_max(float v, float* red){
  int tid = threadIdx.x;
  __syncthreads();
  red[tid]=v; __syncthreads();
  #pragma unroll
  for (int off=128; off>0; off>>=1){ if (tid<off) red[tid]=fmaxf(red[tid],red[tid+off]); __syncthreads(); }
  return red[0];
}

__device__ __forceinline__ void quant_one(const float* h1, float inv2,
    const float* __restrict__ g, int8_t* __restrict__ xq, float* __restrict__ gam,
    float* red, int m){
  int tid = threadIdx.x;
  float amax = 0.f;
  for (int i=tid;i<HIDDEN;i+=256){ float t = h1[i]*inv2*g[i]; amax = fmaxf(amax, fabsf(t)); }
  float gamma = fmaxf(breduce_max(amax, red), 1e-10f);
  float sc = 127.0f/gamma;
  for (int i=tid;i<HIDDEN;i+=256){
    float t = rintf(h1[i]*inv2*g[i]*sc);
    t = fminf(127.f, fmaxf(-128.f, t));
    xq[(size_t)m*HIDDEN + i] = (int8_t)t;
  }
  if (tid==0) gam[m] = gamma;
}

__global__ __launch_bounds__(256) void token_prep_kernel(
    const float* __restrict__ x, const float* __restrict__ nw,
    const float* __restrict__ qg, const float* __restrict__ kg, const float* __restrict__ vg,
    int8_t* __restrict__ xqq, int8_t* __restrict__ xqk, int8_t* __restrict__ xqv,
    float* __restrict__ gq, float* __restrict__ gk, float* __restrict__ gv){
  __shared__ float h1[HIDDEN];
  __shared__ float red[256];
  int m = blockIdx.x, tid = threadIdx.x;
  const float* xr = x + (size_t)m*HIDDEN;
  float ss = 0.f;
  for (int i=tid;i<HIDDEN;i+=256){ float t = xr[i]; ss += t*t; }
  float rms1 = sqrtf(breduce_sum(ss, red)*(1.0f/HIDDEN) + 1e-6f);
  float inv1 = 1.0f/rms1;
  float ss2 = 0.f;
  for (int i=tid;i<HIDDEN;i+=256){ float t = xr[i]*inv1*nw[i]; h1[i]=t; ss2 += t*t; }
  float rms2 = sqrtf(breduce_sum(ss2, red)*(1.0f/HIDDEN) + 1e-6f);
  float inv2 = 1.0f/rms2;
  quant_one(h1, inv2, qg, xqq, gq, red, m);
  quant_one(h1, inv2, kg, xqk, gk, red, m);
  quant_one(h1, inv2, vg, xqv, gv, red, m);
}

__global__ __launch_bounds__(256) void o_prep_kernel(const float* __restrict__ ao,
    const float* __restrict__ og, int8_t* __restrict__ xqo, float* __restrict__ go){
  __shared__ float h1[HIDDEN];
  __shared__ float red[256];
  int m = blockIdx.x, tid = threadIdx.x;
  const float* xr = ao + (size_t)m*HIDDEN;
  float ss = 0.f;
  for (int i=tid;i<HIDDEN;i+=256){ float t = xr[i]; h1[i]=t; ss += t*t; }
  float rms = sqrtf(breduce_sum(ss,red)*(1.0f/HIDDEN)+1e-6f);
  quant_one(h1, 1.0f/rms, og, xqo, go, red, m);
}

// ---------------------------------------------------------------------------
// MFMA i8 GEMM. block = 256 thr (4 waves); wave w: rows [m0+32w,+32) x cols [n0,+64).
// C/D: col=lane&31, row=(reg&3)+8*(reg>>2)+4*(lane>>5)  [m74/m101 verified].
// mode 0: outf[m*640+n] = val + resid                     (O projection, fp32)
// mode 1: rope, scale, outh[b][head][l][d] f16            (Q: vscale=0.125, K: 1.0)
// mode 2: no rope, outh[b][head][d][l] f16 (V TRANSPOSED for attention B-frags)
__global__ __launch_bounds__(256) void mfma_gemm_kernel(
    const int8_t* __restrict__ xq, const float* __restrict__ gam,
    const int8_t* __restrict__ wq,
    const float* __restrict__ sums, int aidx, float inv_nw,
    const float* __restrict__ resid, float* __restrict__ outf,
    _Float16* __restrict__ outh,
    int nheads, int mode, float vscale){
  int lane = threadIdx.x & 63;
  int w    = threadIdx.x >> 6;
  int m0   = blockIdx.y*128 + w*32;
  int n0   = blockIdx.x*64;
  int half = lane >> 5;
  int lan5 = lane & 31;

  const int8_t* arow  = xq + (size_t)(m0 + lan5)*HIDDEN + half*16;
  const int8_t* brow0 = wq + (size_t)(n0      + lan5)*HIDDEN + half*16;
  const int8_t* brow1 = wq + (size_t)(n0 + 32 + lan5)*HIDDEN + half*16;

  int16v acc0 = {0}, acc1 = {0};
  #pragma unroll
  for (int kk=0; kk<HIDDEN; kk+=32){
    int4v a  = *(const int4v*)(arow  + kk);
    int4v b0 = *(const int4v*)(brow0 + kk);
    int4v b1 = *(const int4v*)(brow1 + kk);
    acc0 = __builtin_amdgcn_mfma_i32_32x32x32_i8(a, b0, acc0, 0, 0, 0);
    acc1 = __builtin_amdgcn_mfma_i32_32x32x32_i8(a, b1, acc1, 0, 0, 0);
  }

  float alpha = fmaxf(sums[aidx]*inv_nw, 1e-10f);
  float fr0 = 0.f, fr1 = 0.f;
  if (mode == 1){
    int d0 = (lan5) & ~1;
    int d1 = (32 + lan5) & ~1;
    fr0 = __expf(-(float)d0*(1.0f/64.0f)*13.122363377404328f);
    fr1 = __expf(-(float)d1*(1.0f/64.0f)*13.122363377404328f);
  }

  #pragma unroll
  for (int reg=0; reg<16; reg++){
    int m = m0 + (reg&3) + 8*(reg>>2) + 4*half;
    float sc = alpha*gam[m]*(1.0f/127.0f);
    float v0 = (float)acc0[reg]*sc;
    float v1 = (float)acc1[reg]*sc;
    if (mode == 0){
      size_t ofs = (size_t)m*HIDDEN;
      outf[ofs + n0 + lan5]      = v0 + resid[ofs + n0 + lan5];
      outf[ofs + n0 + 32 + lan5] = v1 + resid[ofs + n0 + 32 + lan5];
    } else {
      int b = m >> 9, l = m & 511;
      int head = n0 >> 6;
      if (mode == 1){
        float p0 = __shfl_xor(v0, 1);
        float p1 = __shfl_xor(v1, 1);
        float sn0, cs0, sn1, cs1;
        __sincosf((float)l*fr0, &sn0, &cs0);
        __sincosf((float)l*fr1, &sn1, &cs1);
        if (lane & 1){ v0 = v0*cs0 + p0*sn0;  v1 = v1*cs1 + p1*sn1; }
        else         { v0 = v0*cs0 - p0*sn0;  v1 = v1*cs1 - p1*sn1; }
        _Float16* dst = outh + ((((size_t)b*nheads + head)*LSEQ + l)<<6);
        dst[lan5]      = (_Float16)(v0*vscale);
        dst[32 + lan5] = (_Float16)(v1*vscale);
      } else {
        // mode 2: V^T  [b][head][d][l]
        _Float16* dst = outh + (((size_t)b*nheads + head)*HDIM)*LSEQ;
        dst[(size_t)(lan5)*LSEQ + l]      = (_Float16)v0;
        dst[(size_t)(32+lan5)*LSEQ + l]   = (_Float16)v1;
      }
    }
  }
}

// ---------------------------------------------------------------------------
// Flash attention via mfma_f32_16x16x32_f16.
// Block = 256 (4 waves); block owns (b, h, 64 q-rows); wave owns 16 q-rows.
// QK^T: A = Q (pre-scaled 1/8), B = K, both straight from global (16B/lane).
// P: C-layout -> LDS (f16, stride 72) -> A-layout.  PV: B = V^T from global.
// A-frag: m=lane&15, k=quad*8+j.  C/D: col=lane&15, row=quad*4+reg. [m89/m120]
__global__ __launch_bounds__(256) void attn_mfma_kernel(
    const _Float16* __restrict__ q, const _Float16* __restrict__ k,
    const _Float16* __restrict__ vt, float* __restrict__ o){
  __shared__ _Float16 Ps[4][16][72];
  int tid  = threadIdx.x;
  int wv   = tid >> 6, lane = tid & 63;
  int quad = lane >> 4, c = lane & 15;
  int qt = blockIdx.x, h = blockIdx.y, b = blockIdx.z;
  int hk = h / GROUPS;
  int qrow0 = (qt<<6) + (wv<<4);

  const _Float16* qb = q + ((size_t)((b*NQH+h)*LSEQ) + qrow0 + c)*HDIM + quad*8;
  f16x8 qf0 = *(const f16x8*)qb;
  f16x8 qf1 = *(const f16x8*)(qb + 32);
  const _Float16* kb = k  + (size_t)((b*NKVH+hk)*LSEQ)*HDIM;
  const _Float16* vb = vt + (size_t)((b*NKVH+hk)*HDIM)*LSEQ;

  f32x4 Oacc[4] = {{0,0,0,0},{0,0,0,0},{0,0,0,0},{0,0,0,0}};
  float m_i[4] = {-INFINITY,-INFINITY,-INFINITY,-INFINITY};
  float l_i[4] = {0.f,0.f,0.f,0.f};

  for (int kt=0; kt<8; kt++){
    f32x4 S[4];
    #pragma unroll
    for (int nt=0; nt<4; nt++){
      const _Float16* kr = kb + (size_t)((kt<<6)+(nt<<4)+c)*HDIM + quad*8;
      f16x8 kf0 = *(const f16x8*)kr;
      f16x8 kf1 = *(const f16x8*)(kr + 32);
      f32x4 s = {0,0,0,0};
      s = __builtin_amdgcn_mfma_f32_16x16x32_f16(qf0, kf0, s, 0,0,0);
      s = __builtin_amdgcn_mfma_f32_16x16x32_f16(qf1, kf1, s, 0,0,0);
      S[nt] = s;
    }
    #pragma unroll
    for (int r=0;r<4;r++){
      float mx = fmaxf(fmaxf(S[0][r],S[1][r]), fmaxf(S[2][r],S[3][r]));
      mx = fmaxf(mx, __shfl_xor(mx,1));
      mx = fmaxf(mx, __shfl_xor(mx,2));
      mx = fmaxf(mx, __shfl_xor(mx,4));
      mx = fmaxf(mx, __shfl_xor(mx,8));
      float mnew = fmaxf(m_i[r], mx);
      float af = __expf(m_i[r] - mnew);
      m_i[r] = mnew;
      float ps = 0.f;
      #pragma unroll
      for (int nt=0;nt<4;nt++){
        float p = __expf(S[nt][r] - mnew);
        ps += p;
        Ps[wv][(quad<<2)+r][(nt<<4)+c] = (_Float16)p;
      }
      ps += __shfl_xor(ps,1);
      ps += __shfl_xor(ps,2);
      ps += __shfl_xor(ps,4);
      ps += __shfl_xor(ps,8);
      l_i[r] = l_i[r]*af + ps;
      Oacc[0][r]*=af; Oacc[1][r]*=af; Oacc[2][r]*=af; Oacc[3][r]*=af;
    }
    // wave-internal LDS round-trip (C-layout -> A-layout); no barrier needed,
    // compiler inserts lgkmcnt for may-alias LDS ops.
    f16x8 pf0 = *(const f16x8*)&Ps[wv][c][quad*8];
    f16x8 pf1 = *(const f16x8*)&Ps[wv][c][quad*8 + 32];
    #pragma unroll
    for (int nt=0;nt<4;nt++){
      const _Float16* vr = vb + (size_t)((nt<<4)+c)*LSEQ + (kt<<6) + quad*8;
      f16x8 vf0 = *(const f16x8*)vr;
      f16x8 vf1 = *(const f16x8*)(vr + 32);
      Oacc[nt] = __builtin_amdgcn_mfma_f32_16x16x32_f16(pf0, vf0, Oacc[nt], 0,0,0);
      Oacc[nt] = __builtin_amdgcn_mfma_f32_16x16x32_f16(pf1, vf1, Oacc[nt], 0,0,0);
    }
  }
  #pragma unroll
  for (int r=0;r<4;r++){
    float invl = 1.0f/l_i[r];
    int m = (b<<9) + qrow0 + (quad<<2) + r;
    float* dst = o + (size_t)m*HIDDEN + (h<<6);
    #pragma unroll
    for (int nt=0;nt<4;nt++) dst[(nt<<4)+c] = Oacc[nt][r]*invl;
  }
}

// ---------------------------------------------------------------------------
extern "C" void kernel_launch(void* const* d_in, const int* in_sizes, int n_in,
                              void* d_out, int out_size, void* d_ws, size_t ws_size,
                              hipStream_t stream){
  (void)in_sizes; (void)n_in; (void)out_size; (void)ws_size;
  const float* x  = (const float*)d_in[0];
  const float* nw = (const float*)d_in[1];
  const float* qw = (const float*)d_in[2];
  const float* qg = (const float*)d_in[3];
  const float* kw = (const float*)d_in[4];
  const float* kg = (const float*)d_in[5];
  const float* vw = (const float*)d_in[6];
  const float* vg = (const float*)d_in[7];
  const float* ow = (const float*)d_in[8];
  const float* og = (const float*)d_in[9];
  float* out = (float*)d_out;

  char* base = (char*)d_ws;
  size_t off = 0;
  auto alloc = [&](size_t nbytes)->void*{
    off = (off + 255) & ~(size_t)255;
    void* p = base + off;
    off += nbytes;
    return p;
  };
  float*  sums = (float*) alloc(4*sizeof(float));
  int8_t* wq_q = (int8_t*)alloc(640*640);
  int8_t* wq_k = (int8_t*)alloc(128*640);
  int8_t* wq_v = (int8_t*)alloc(128*640);
  int8_t* wq_o = (int8_t*)alloc(640*640);
  int8_t* xq_q = (int8_t*)alloc((size_t)NTOK*HIDDEN);
  int8_t* xq_k = (int8_t*)alloc((size_t)NTOK*HIDDEN);
  int8_t* xq_v = (int8_t*)alloc((size_t)NTOK*HIDDEN);
  int8_t* xq_o = (int8_t*)alloc((size_t)NTOK*HIDDEN);
  float*  g_q  = (float*) alloc((size_t)NTOK*4);
  float*  g_k  = (float*) alloc((size_t)NTOK*4);
  float*  g_v  = (float*) alloc((size_t)NTOK*4);
  float*  g_o  = (float*) alloc((size_t)NTOK*4);
  _Float16* qbuf = (_Float16*)alloc((size_t)BATCH*NQH *LSEQ*HDIM*2);
  _Float16* kbuf = (_Float16*)alloc((size_t)BATCH*NKVH*LSEQ*HDIM*2);
  _Float16* vbuf = (_Float16*)alloc((size_t)BATCH*NKVH*LSEQ*HDIM*2);
  float*  abuf = (float*) alloc((size_t)NTOK*HIDDEN*4);

  (void)hipMemsetAsync(sums, 0, 4*sizeof(float), stream);
  absum_kernel<<<256,256,0,stream>>>(qw, 640*640, sums+0);
  absum_kernel<<<256,256,0,stream>>>(kw, 128*640, sums+1);
  absum_kernel<<<256,256,0,stream>>>(vw, 128*640, sums+2);
  absum_kernel<<<256,256,0,stream>>>(ow, 640*640, sums+3);
  wquant_kernel<<<(640*640+255)/256,256,0,stream>>>(qw, wq_q, 640*640, sums, 0, 1.0f/(640.f*640.f));
  wquant_kernel<<<(128*640+255)/256,256,0,stream>>>(kw, wq_k, 128*640, sums, 1, 1.0f/(128.f*640.f));
  wquant_kernel<<<(128*640+255)/256,256,0,stream>>>(vw, wq_v, 128*640, sums, 2, 1.0f/(128.f*640.f));
  wquant_kernel<<<(640*640+255)/256,256,0,stream>>>(ow, wq_o, 640*640, sums, 3, 1.0f/(640.f*640.f));

  token_prep_kernel<<<NTOK,256,0,stream>>>(x, nw, qg, kg, vg, xq_q, xq_k, xq_v, g_q, g_k, g_v);

  mfma_gemm_kernel<<<dim3(10,128),256,0,stream>>>(xq_q, g_q, wq_q, sums, 0, 1.0f/(640.f*640.f), nullptr, nullptr, qbuf, NQH, 1, 0.125f);
  mfma_gemm_kernel<<<dim3(2,128),256,0,stream>>>(xq_k, g_k, wq_k, sums, 1, 1.0f/(128.f*640.f), nullptr, nullptr, kbuf, NKVH, 1, 1.0f);
  mfma_gemm_kernel<<<dim3(2,128),256,0,stream>>>(xq_v, g_v, wq_v, sums, 2, 1.0f/(128.f*640.f), nullptr, nullptr, vbuf, NKVH, 2, 1.0f);

  attn_mfma_kernel<<<dim3(8,NQH,BATCH),256,0,stream>>>(qbuf, kbuf, vbuf, abuf);

  o_prep_kernel<<<NTOK,256,0,stream>>>(abuf, og, xq_o, g_o);
  mfma_gemm_kernel<<<dim3(10,128),256,0,stream>>>(xq_o, g_o, wq_o, sums, 3, 1.0f/(640.f*640.f), x, out, nullptr, 0, 0, 1.0f);
}

// Round 5
// 321.305 us; speedup vs baseline: 8.1592x; 1.6254x over previous
//
#include <hip/hip_runtime.h>
#include <math.h>
#include <stdint.h>

#define HIDDEN 640
#define NTOK   16384   // 32*512
#define LSEQ   512
#define BATCH  32
#define NQH    10
#define NKVH   2
#define HDIM   64
#define GROUPS 5

typedef int      int4v  __attribute__((ext_vector_type(4)));
typedef int      int16v __attribute__((ext_vector_type(16)));
typedef _Float16 f16x8  __attribute__((ext_vector_type(8)));
typedef float    f32x4  __attribute__((ext_vector_type(4)));

// ---------------------------------------------------------------------------
// wave-wide reductions (64 lanes, shuffle-only, no barriers)
__device__ __forceinline__ float wred_sum(float v){
  #pragma unroll
  for (int m=1;m<64;m<<=1) v += __shfl_xor(v,m);
  return v;
}
__device__ __forceinline__ float wred_max(float v){
  #pragma unroll
  for (int m=1;m<64;m<<=1) v = fmaxf(v,__shfl_xor(v,m));
  return v;
}

// ---------------------------------------------------------------------------
// fused |w| sums for all 4 weight tensors: grid (64, 4), blockIdx.y = tensor
__global__ __launch_bounds__(256) void absum4_kernel(
    const float* __restrict__ w0, const float* __restrict__ w1,
    const float* __restrict__ w2, const float* __restrict__ w3,
    float* __restrict__ sums){
  const float* w; int n;
  switch(blockIdx.y){
    case 0:  w=w0; n=640*640; break;
    case 1:  w=w1; n=128*640; break;
    case 2:  w=w2; n=128*640; break;
    default: w=w3; n=640*640; break;
  }
  __shared__ float red[256];
  int tid = threadIdx.x;
  float s = 0.f;
  for (int i = blockIdx.x*256 + tid; i < n; i += gridDim.x*256) s += fabsf(w[i]);
  red[tid] = s; __syncthreads();
  for (int off=128; off>0; off>>=1){ if (tid<off) red[tid]+=red[tid+off]; __syncthreads(); }
  if (tid==0) atomicAdd(&sums[blockIdx.y], red[0]);
}

// fused weight ternarization: grid (1600, 4)
__global__ __launch_bounds__(256) void wquant4_kernel(
    const float* __restrict__ w0, const float* __restrict__ w1,
    const float* __restrict__ w2, const float* __restrict__ w3,
    int8_t* __restrict__ o0, int8_t* __restrict__ o1,
    int8_t* __restrict__ o2, int8_t* __restrict__ o3,
    const float* __restrict__ sums){
  const float* w; int8_t* o; int n;
  switch(blockIdx.y){
    case 0:  w=w0; o=o0; n=640*640; break;
    case 1:  w=w1; o=o1; n=128*640; break;
    case 2:  w=w2; o=o2; n=128*640; break;
    default: w=w3; o=o3; n=640*640; break;
  }
  float alpha = fmaxf(sums[blockIdx.y]/(float)n, 1e-10f);
  float inva  = 1.0f/alpha;
  int i = blockIdx.x*256 + threadIdx.x;
  if (i < n){
    float t = rintf(w[i]*inva);            // round-half-even matches jnp.round
    t = fminf(1.f, fmaxf(-1.f, t));
    o[i] = (int8_t)t;
  }
}

// ---------------------------------------------------------------------------
// wave-per-token prep: double rmsnorm + 3x int8 quant, all register-resident.
// block = 256 (4 waves = 4 tokens); grid = NTOK/4.
__global__ __launch_bounds__(256) void token_prep_kernel(
    const float* __restrict__ x, const float* __restrict__ nw,
    const float* __restrict__ qg, const float* __restrict__ kg, const float* __restrict__ vg,
    int8_t* __restrict__ xqq, int8_t* __restrict__ xqk, int8_t* __restrict__ xqv,
    float* __restrict__ gq, float* __restrict__ gk, float* __restrict__ gv){
  int lane = threadIdx.x & 63;
  int m = blockIdx.x*4 + (threadIdx.x>>6);
  const float* xr = x + (size_t)m*HIDDEN;
  float xv[10], h[10];
  float ss = 0.f;
  #pragma unroll
  for (int j=0;j<10;j++){ float t = xr[lane + 64*j]; xv[j]=t; ss += t*t; }
  float inv1 = 1.0f/sqrtf(wred_sum(ss)*(1.0f/HIDDEN) + 1e-6f);
  float ss2 = 0.f;
  #pragma unroll
  for (int j=0;j<10;j++){ float t = xv[j]*inv1*nw[lane+64*j]; h[j]=t; ss2 += t*t; }
  float inv2 = 1.0f/sqrtf(wred_sum(ss2)*(1.0f/HIDDEN) + 1e-6f);

  const float* gs[3] = {qg, kg, vg};
  int8_t* outs[3] = {xqq, xqk, xqv};
  float* gams[3] = {gq, gk, gv};
  #pragma unroll
  for (int s=0;s<3;s++){
    const float* g = gs[s];
    float t[10], amax = 0.f;
    #pragma unroll
    for (int j=0;j<10;j++){ float v = h[j]*inv2*g[lane+64*j]; t[j]=v; amax = fmaxf(amax, fabsf(v)); }
    float gamma = fmaxf(wred_max(amax), 1e-10f);
    float sc = 127.0f/gamma;
    int8_t* dst = outs[s] + (size_t)m*HIDDEN;
    #pragma unroll
    for (int j=0;j<10;j++){
      float v = rintf(t[j]*sc);
      v = fminf(127.f, fmaxf(-128.f, v));
      dst[lane+64*j] = (int8_t)v;
    }
    if (lane==0) gams[s][m] = gamma;
  }
}

// wave-per-token O-prep: single rmsnorm + quant
__global__ __launch_bounds__(256) void o_prep_kernel(const float* __restrict__ ao,
    const float* __restrict__ og, int8_t* __restrict__ xqo, float* __restrict__ go){
  int lane = threadIdx.x & 63;
  int m = blockIdx.x*4 + (threadIdx.x>>6);
  const float* xr = ao + (size_t)m*HIDDEN;
  float xv[10];
  float ss = 0.f;
  #pragma unroll
  for (int j=0;j<10;j++){ float t = xr[lane + 64*j]; xv[j]=t; ss += t*t; }
  float inv = 1.0f/sqrtf(wred_sum(ss)*(1.0f/HIDDEN) + 1e-6f);
  float t[10], amax = 0.f;
  #pragma unroll
  for (int j=0;j<10;j++){ float v = xv[j]*inv*og[lane+64*j]; t[j]=v; amax = fmaxf(amax, fabsf(v)); }
  float gamma = fmaxf(wred_max(amax), 1e-10f);
  float sc = 127.0f/gamma;
  int8_t* dst = xqo + (size_t)m*HIDDEN;
  #pragma unroll
  for (int j=0;j<10;j++){
    float v = rintf(t[j]*sc);
    v = fminf(127.f, fmaxf(-128.f, v));
    dst[lane+64*j] = (int8_t)v;
  }
  if (lane==0) go[m] = gamma;
}

// ---------------------------------------------------------------------------
// MFMA i8 GEMM (unchanged from R4).
// mode 0: outf[m*640+n] = val + resid          (O projection, fp32)
// mode 1: rope, scale, outh[b][head][l][d] f16 (Q: vscale=0.125, K: 1.0)
// mode 2: no rope, outh[b][head][d][l] f16     (V transposed)
__global__ __launch_bounds__(256) void mfma_gemm_kernel(
    const int8_t* __restrict__ xq, const float* __restrict__ gam,
    const int8_t* __restrict__ wq,
    const float* __restrict__ sums, int aidx, float inv_nw,
    const float* __restrict__ resid, float* __restrict__ outf,
    _Float16* __restrict__ outh,
    int nheads, int mode, float vscale){
  int lane = threadIdx.x & 63;
  int w    = threadIdx.x >> 6;
  int m0   = blockIdx.y*128 + w*32;
  int n0   = blockIdx.x*64;
  int half = lane >> 5;
  int lan5 = lane & 31;

  const int8_t* arow  = xq + (size_t)(m0 + lan5)*HIDDEN + half*16;
  const int8_t* brow0 = wq + (size_t)(n0      + lan5)*HIDDEN + half*16;
  const int8_t* brow1 = wq + (size_t)(n0 + 32 + lan5)*HIDDEN + half*16;

  int16v acc0 = {0}, acc1 = {0};
  #pragma unroll
  for (int kk=0; kk<HIDDEN; kk+=32){
    int4v a  = *(const int4v*)(arow  + kk);
    int4v b0 = *(const int4v*)(brow0 + kk);
    int4v b1 = *(const int4v*)(brow1 + kk);
    acc0 = __builtin_amdgcn_mfma_i32_32x32x32_i8(a, b0, acc0, 0, 0, 0);
    acc1 = __builtin_amdgcn_mfma_i32_32x32x32_i8(a, b1, acc1, 0, 0, 0);
  }

  float alpha = fmaxf(sums[aidx]*inv_nw, 1e-10f);
  float fr0 = 0.f, fr1 = 0.f;
  if (mode == 1){
    int d0 = (lan5) & ~1;
    int d1 = (32 + lan5) & ~1;
    fr0 = __expf(-(float)d0*(1.0f/64.0f)*13.122363377404328f);
    fr1 = __expf(-(float)d1*(1.0f/64.0f)*13.122363377404328f);
  }

  #pragma unroll
  for (int reg=0; reg<16; reg++){
    int m = m0 + (reg&3) + 8*(reg>>2) + 4*half;
    float sc = alpha*gam[m]*(1.0f/127.0f);
    float v0 = (float)acc0[reg]*sc;
    float v1 = (float)acc1[reg]*sc;
    if (mode == 0){
      size_t ofs = (size_t)m*HIDDEN;
      outf[ofs + n0 + lan5]      = v0 + resid[ofs + n0 + lan5];
      outf[ofs + n0 + 32 + lan5] = v1 + resid[ofs + n0 + 32 + lan5];
    } else {
      int b = m >> 9, l = m & 511;
      int head = n0 >> 6;
      if (mode == 1){
        float p0 = __shfl_xor(v0, 1);
        float p1 = __shfl_xor(v1, 1);
        float sn0, cs0, sn1, cs1;
        __sincosf((float)l*fr0, &sn0, &cs0);
        __sincosf((float)l*fr1, &sn1, &cs1);
        if (lane & 1){ v0 = v0*cs0 + p0*sn0;  v1 = v1*cs1 + p1*sn1; }
        else         { v0 = v0*cs0 - p0*sn0;  v1 = v1*cs1 - p1*sn1; }
        _Float16* dst = outh + ((((size_t)b*nheads + head)*LSEQ + l)<<6);
        dst[lan5]      = (_Float16)(v0*vscale);
        dst[32 + lan5] = (_Float16)(v1*vscale);
      } else {
        _Float16* dst = outh + (((size_t)b*nheads + head)*HDIM)*LSEQ;
        dst[(size_t)(lan5)*LSEQ + l]      = (_Float16)v0;
        dst[(size_t)(32+lan5)*LSEQ + l]   = (_Float16)v1;
      }
    }
  }
}

// ---------------------------------------------------------------------------
// Flash attention v2: block-cooperative LDS staging of K and V^T tiles,
// XOR-swizzled chunk layout (16B chunks; chunk' = chunk ^ (row&7), no pad ->
// 16B aligned, conflict-free per consecutive-lane-group). Register prefetch
// of tile kt+1 between the barriers.
// Block = 256 (4 waves) owns (b, h, 64 q-rows); wave owns 16 q-rows.
// A-frag: m=lane&15, k=quad*8+j.  C/D: col=lane&15, row=quad*4+reg.
__device__ __forceinline__ int kv_addr(int row, int chunk){  // in halves
  return (row<<6) + (((chunk ^ (row&7)))<<3);
}

__global__ __launch_bounds__(256,2) void attn_mfma_kernel(
    const _Float16* __restrict__ q, const _Float16* __restrict__ k,
    const _Float16* __restrict__ vt, float* __restrict__ o){
  __shared__ _Float16 Ks[64*64];
  __shared__ _Float16 Vs[64*64];
  __shared__ _Float16 Ps[4][16][72];
  int tid  = threadIdx.x;
  int wv   = tid >> 6, lane = tid & 63;
  int quad = lane >> 4, c = lane & 15;
  int qt = blockIdx.x, h = blockIdx.y, b = blockIdx.z;
  int hk = h / GROUPS;
  int qrow0 = (qt<<6) + (wv<<4);

  const _Float16* qb = q + ((size_t)((b*NQH+h)*LSEQ) + qrow0 + c)*HDIM + quad*8;
  f16x8 qf0 = *(const f16x8*)qb;
  f16x8 qf1 = *(const f16x8*)(qb + 32);

  const _Float16* kbase = k  + (size_t)((b*NKVH+hk)*LSEQ)*HDIM;  // [l][d]
  const _Float16* vbase = vt + (size_t)((b*NKVH+hk)*HDIM)*LSEQ;  // [d][l]

  // staging: thread t loads rows (t>>3) and (t>>3)+32, 16B chunk t&7
  int srow = tid >> 3, schunk = tid & 7;
  const _Float16* kg0 = kbase + (size_t)srow*HDIM      + schunk*8;
  const _Float16* kg1 = kbase + (size_t)(srow+32)*HDIM + schunk*8;
  const _Float16* vg0 = vbase + (size_t)srow*LSEQ      + schunk*8;
  const _Float16* vg1 = vbase + (size_t)(srow+32)*LSEQ + schunk*8;
  int ka0 = kv_addr(srow,    schunk);
  int ka1 = kv_addr(srow+32, schunk);

  f16x8 pk0 = *(const f16x8*)kg0;
  f16x8 pk1 = *(const f16x8*)kg1;
  f16x8 pv0 = *(const f16x8*)vg0;
  f16x8 pv1 = *(const f16x8*)vg1;

  f32x4 Oacc[4] = {{0,0,0,0},{0,0,0,0},{0,0,0,0},{0,0,0,0}};
  float m_i[4] = {-INFINITY,-INFINITY,-INFINITY,-INFINITY};
  float l_i[4] = {0.f,0.f,0.f,0.f};

  for (int kt=0; kt<8; kt++){
    *(f16x8*)&Ks[ka0] = pk0;
    *(f16x8*)&Ks[ka1] = pk1;
    *(f16x8*)&Vs[ka0] = pv0;
    *(f16x8*)&Vs[ka1] = pv1;
    __syncthreads();
    if (kt < 7){
      pk0 = *(const f16x8*)(kg0 + (size_t)(kt+1)*64*HDIM);
      pk1 = *(const f16x8*)(kg1 + (size_t)(kt+1)*64*HDIM);
      pv0 = *(const f16x8*)(vg0 + (kt+1)*64);
      pv1 = *(const f16x8*)(vg1 + (kt+1)*64);
    }
    // S = Q K^T (per-wave, B-frags from swizzled LDS)
    f32x4 S[4];
    #pragma unroll
    for (int nt=0; nt<4; nt++){
      int row = (nt<<4) + c;
      f16x8 kf0 = *(const f16x8*)&Ks[kv_addr(row, quad)];
      f16x8 kf1 = *(const f16x8*)&Ks[kv_addr(row, quad+4)];
      f32x4 s = {0,0,0,0};
      s = __builtin_amdgcn_mfma_f32_16x16x32_f16(qf0, kf0, s, 0,0,0);
      s = __builtin_amdgcn_mfma_f32_16x16x32_f16(qf1, kf1, s, 0,0,0);
      S[nt] = s;
    }
    // online softmax (rows r owned by quad; 16 lanes per row-set)
    #pragma unroll
    for (int r=0;r<4;r++){
      float mx = fmaxf(fmaxf(S[0][r],S[1][r]), fmaxf(S[2][r],S[3][r]));
      mx = fmaxf(mx, __shfl_xor(mx,1));
      mx = fmaxf(mx, __shfl_xor(mx,2));
      mx = fmaxf(mx, __shfl_xor(mx,4));
      mx = fmaxf(mx, __shfl_xor(mx,8));
      float mnew = fmaxf(m_i[r], mx);
      float af = __expf(m_i[r] - mnew);
      m_i[r] = mnew;
      float ps = 0.f;
      #pragma unroll
      for (int nt=0;nt<4;nt++){
        float p = __expf(S[nt][r] - mnew);
        ps += p;
        Ps[wv][(quad<<2)+r][(nt<<4)+c] = (_Float16)p;
      }
      ps += __shfl_xor(ps,1);
      ps += __shfl_xor(ps,2);
      ps += __shfl_xor(ps,4);
      ps += __shfl_xor(ps,8);
      l_i[r] = l_i[r]*af + ps;
      Oacc[0][r]*=af; Oacc[1][r]*=af; Oacc[2][r]*=af; Oacc[3][r]*=af;
    }
    // P: C-layout -> A-layout via wave-local LDS slab
    f16x8 pf0 = *(const f16x8*)&Ps[wv][c][quad*8];
    f16x8 pf1 = *(const f16x8*)&Ps[wv][c][quad*8 + 32];
    #pragma unroll
    for (int nt=0;nt<4;nt++){
      int row = (nt<<4) + c;   // d index
      f16x8 vf0 = *(const f16x8*)&Vs[kv_addr(row, quad)];
      f16x8 vf1 = *(const f16x8*)&Vs[kv_addr(row, quad+4)];
      Oacc[nt] = __builtin_amdgcn_mfma_f32_16x16x32_f16(pf0, vf0, Oacc[nt], 0,0,0);
      Oacc[nt] = __builtin_amdgcn_mfma_f32_16x16x32_f16(pf1, vf1, Oacc[nt], 0,0,0);
    }
    __syncthreads();
  }
  #pragma unroll
  for (int r=0;r<4;r++){
    float invl = 1.0f/l_i[r];
    int m = (b<<9) + qrow0 + (quad<<2) + r;
    float* dst = o + (size_t)m*HIDDEN + (h<<6);
    #pragma unroll
    for (int nt=0;nt<4;nt++) dst[(nt<<4)+c] = Oacc[nt][r]*invl;
  }
}

// ---------------------------------------------------------------------------
extern "C" void kernel_launch(void* const* d_in, const int* in_sizes, int n_in,
                              void* d_out, int out_size, void* d_ws, size_t ws_size,
                              hipStream_t stream){
  (void)in_sizes; (void)n_in; (void)out_size; (void)ws_size;
  const float* x  = (const float*)d_in[0];
  const float* nw = (const float*)d_in[1];
  const float* qw = (const float*)d_in[2];
  const float* qg = (const float*)d_in[3];
  const float* kw = (const float*)d_in[4];
  const float* kg = (const float*)d_in[5];
  const float* vw = (const float*)d_in[6];
  const float* vg = (const float*)d_in[7];
  const float* ow = (const float*)d_in[8];
  const float* og = (const float*)d_in[9];
  float* out = (float*)d_out;

  char* base = (char*)d_ws;
  size_t off = 0;
  auto alloc = [&](size_t nbytes)->void*{
    off = (off + 255) & ~(size_t)255;
    void* p = base + off;
    off += nbytes;
    return p;
  };
  float*  sums = (float*) alloc(4*sizeof(float));
  int8_t* wq_q = (int8_t*)alloc(640*640);
  int8_t* wq_k = (int8_t*)alloc(128*640);
  int8_t* wq_v = (int8_t*)alloc(128*640);
  int8_t* wq_o = (int8_t*)alloc(640*640);
  int8_t* xq_q = (int8_t*)alloc((size_t)NTOK*HIDDEN);
  int8_t* xq_k = (int8_t*)alloc((size_t)NTOK*HIDDEN);
  int8_t* xq_v = (int8_t*)alloc((size_t)NTOK*HIDDEN);
  int8_t* xq_o = (int8_t*)alloc((size_t)NTOK*HIDDEN);
  float*  g_q  = (float*) alloc((size_t)NTOK*4);
  float*  g_k  = (float*) alloc((size_t)NTOK*4);
  float*  g_v  = (float*) alloc((size_t)NTOK*4);
  float*  g_o  = (float*) alloc((size_t)NTOK*4);
  _Float16* qbuf = (_Float16*)alloc((size_t)BATCH*NQH *LSEQ*HDIM*2);
  _Float16* kbuf = (_Float16*)alloc((size_t)BATCH*NKVH*LSEQ*HDIM*2);
  _Float16* vbuf = (_Float16*)alloc((size_t)BATCH*NKVH*LSEQ*HDIM*2);
  float*  abuf = (float*) alloc((size_t)NTOK*HIDDEN*4);

  (void)hipMemsetAsync(sums, 0, 4*sizeof(float), stream);
  absum4_kernel<<<dim3(64,4),256,0,stream>>>(qw, kw, vw, ow, sums);
  wquant4_kernel<<<dim3(1600,4),256,0,stream>>>(qw, kw, vw, ow, wq_q, wq_k, wq_v, wq_o, sums);

  token_prep_kernel<<<NTOK/4,256,0,stream>>>(x, nw, qg, kg, vg, xq_q, xq_k, xq_v, g_q, g_k, g_v);

  mfma_gemm_kernel<<<dim3(10,128),256,0,stream>>>(xq_q, g_q, wq_q, sums, 0, 1.0f/(640.f*640.f), nullptr, nullptr, qbuf, NQH, 1, 0.125f);
  mfma_gemm_kernel<<<dim3(2,128),256,0,stream>>>(xq_k, g_k, wq_k, sums, 1, 1.0f/(128.f*640.f), nullptr, nullptr, kbuf, NKVH, 1, 1.0f);
  mfma_gemm_kernel<<<dim3(2,128),256,0,stream>>>(xq_v, g_v, wq_v, sums, 2, 1.0f/(128.f*640.f), nullptr, nullptr, vbuf, NKVH, 2, 1.0f);

  attn_mfma_kernel<<<dim3(8,NQH,BATCH),256,0,stream>>>(qbuf, kbuf, vbuf, abuf);

  o_prep_kernel<<<NTOK/4,256,0,stream>>>(abuf, og, xq_o, g_o);
  mfma_gemm_kernel<<<dim3(10,128),256,0,stream>>>(xq_o, g_o, wq_o, sums, 3, 1.0f/(640.f*640.f), x, out, nullptr, 0, 0, 1.0f);
}

// Round 6
// 320.099 us; speedup vs baseline: 8.1899x; 1.0038x over previous
//
#include <hip/hip_runtime.h>
#include <math.h>
#include <stdint.h>

#define HIDDEN 640
#define NTOK   16384   // 32*512
#define LSEQ   512
#define BATCH  32
#define NQH    10
#define NKVH   2
#define HDIM   64
#define GROUPS 5

typedef int      int4v  __attribute__((ext_vector_type(4)));
typedef int      int16v __attribute__((ext_vector_type(16)));
typedef _Float16 f16x8  __attribute__((ext_vector_type(8)));
typedef float    f32x4  __attribute__((ext_vector_type(4)));

// ---------------------------------------------------------------------------
__device__ __forceinline__ float wred_sum(float v){
  #pragma unroll
  for (int m=1;m<64;m<<=1) v += __shfl_xor(v,m);
  return v;
}
__device__ __forceinline__ float wred_max(float v){
  #pragma unroll
  for (int m=1;m<64;m<<=1) v = fmaxf(v,__shfl_xor(v,m));
  return v;
}

// ---------------------------------------------------------------------------
__global__ __launch_bounds__(256) void absum4_kernel(
    const float* __restrict__ w0, const float* __restrict__ w1,
    const float* __restrict__ w2, const float* __restrict__ w3,
    float* __restrict__ sums){
  const float* w; int n;
  switch(blockIdx.y){
    case 0:  w=w0; n=640*640; break;
    case 1:  w=w1; n=128*640; break;
    case 2:  w=w2; n=128*640; break;
    default: w=w3; n=640*640; break;
  }
  __shared__ float red[256];
  int tid = threadIdx.x;
  float s = 0.f;
  for (int i = blockIdx.x*256 + tid; i < n; i += gridDim.x*256) s += fabsf(w[i]);
  red[tid] = s; __syncthreads();
  for (int off=128; off>0; off>>=1){ if (tid<off) red[tid]+=red[tid+off]; __syncthreads(); }
  if (tid==0) atomicAdd(&sums[blockIdx.y], red[0]);
}

__global__ __launch_bounds__(256) void wquant4_kernel(
    const float* __restrict__ w0, const float* __restrict__ w1,
    const float* __restrict__ w2, const float* __restrict__ w3,
    int8_t* __restrict__ o0, int8_t* __restrict__ o1,
    int8_t* __restrict__ o2, int8_t* __restrict__ o3,
    const float* __restrict__ sums){
  const float* w; int8_t* o; int n;
  switch(blockIdx.y){
    case 0:  w=w0; o=o0; n=640*640; break;
    case 1:  w=w1; o=o1; n=128*640; break;
    case 2:  w=w2; o=o2; n=128*640; break;
    default: w=w3; o=o3; n=640*640; break;
  }
  float alpha = fmaxf(sums[blockIdx.y]/(float)n, 1e-10f);
  float inva  = 1.0f/alpha;
  int i = blockIdx.x*256 + threadIdx.x;
  if (i < n){
    float t = rintf(w[i]*inva);            // round-half-even matches jnp.round
    t = fminf(1.f, fmaxf(-1.f, t));
    o[i] = (int8_t)t;
  }
}

// ---------------------------------------------------------------------------
// wave-per-token prep (register-resident, shuffle reductions)
__global__ __launch_bounds__(256) void token_prep_kernel(
    const float* __restrict__ x, const float* __restrict__ nw,
    const float* __restrict__ qg, const float* __restrict__ kg, const float* __restrict__ vg,
    int8_t* __restrict__ xqq, int8_t* __restrict__ xqk, int8_t* __restrict__ xqv,
    float* __restrict__ gq, float* __restrict__ gk, float* __restrict__ gv){
  int lane = threadIdx.x & 63;
  int m = blockIdx.x*4 + (threadIdx.x>>6);
  const float* xr = x + (size_t)m*HIDDEN;
  float xv[10], h[10];
  float ss = 0.f;
  #pragma unroll
  for (int j=0;j<10;j++){ float t = xr[lane + 64*j]; xv[j]=t; ss += t*t; }
  float inv1 = 1.0f/sqrtf(wred_sum(ss)*(1.0f/HIDDEN) + 1e-6f);
  float ss2 = 0.f;
  #pragma unroll
  for (int j=0;j<10;j++){ float t = xv[j]*inv1*nw[lane+64*j]; h[j]=t; ss2 += t*t; }
  float inv2 = 1.0f/sqrtf(wred_sum(ss2)*(1.0f/HIDDEN) + 1e-6f);

  const float* gs[3] = {qg, kg, vg};
  int8_t* outs[3] = {xqq, xqk, xqv};
  float* gams[3] = {gq, gk, gv};
  #pragma unroll
  for (int s=0;s<3;s++){
    const float* g = gs[s];
    float t[10], amax = 0.f;
    #pragma unroll
    for (int j=0;j<10;j++){ float v = h[j]*inv2*g[lane+64*j]; t[j]=v; amax = fmaxf(amax, fabsf(v)); }
    float gamma = fmaxf(wred_max(amax), 1e-10f);
    float sc = 127.0f/gamma;
    int8_t* dst = outs[s] + (size_t)m*HIDDEN;
    #pragma unroll
    for (int j=0;j<10;j++){
      float v = rintf(t[j]*sc);
      v = fminf(127.f, fmaxf(-128.f, v));
      dst[lane+64*j] = (int8_t)v;
    }
    if (lane==0) gams[s][m] = gamma;
  }
}

// wave-per-token O-prep: reads f16 attn output
__global__ __launch_bounds__(256) void o_prep_kernel(const _Float16* __restrict__ ao,
    const float* __restrict__ og, int8_t* __restrict__ xqo, float* __restrict__ go){
  int lane = threadIdx.x & 63;
  int m = blockIdx.x*4 + (threadIdx.x>>6);
  const _Float16* xr = ao + (size_t)m*HIDDEN;
  float xv[10];
  float ss = 0.f;
  #pragma unroll
  for (int j=0;j<10;j++){ float t = (float)xr[lane + 64*j]; xv[j]=t; ss += t*t; }
  float inv = 1.0f/sqrtf(wred_sum(ss)*(1.0f/HIDDEN) + 1e-6f);
  float t[10], amax = 0.f;
  #pragma unroll
  for (int j=0;j<10;j++){ float v = xv[j]*inv*og[lane+64*j]; t[j]=v; amax = fmaxf(amax, fabsf(v)); }
  float gamma = fmaxf(wred_max(amax), 1e-10f);
  float sc = 127.0f/gamma;
  int8_t* dst = xqo + (size_t)m*HIDDEN;
  #pragma unroll
  for (int j=0;j<10;j++){
    float v = rintf(t[j]*sc);
    v = fminf(127.f, fmaxf(-128.f, v));
    dst[lane+64*j] = (int8_t)v;
  }
  if (lane==0) go[m] = gamma;
}

// ---------------------------------------------------------------------------
// MFMA i8 GEMM. block=256 (4 waves); wave w: rows [m0+32w,+32) x cols [n0,+64).
// C/D: col=lane&31, row=(reg&3)+8*(reg>>2)+4*(lane>>5).
// mode 0: outf[m*640+n] = val + resid              (O projection, fp32)
// mode 1: rope, scale, outh[b][head][l][d] f16     (Q: vscale=0.125, K: 1.0)
// mode 2: V^T via per-wave LDS transpose -> coalesced [b][head][d][l] stores
__global__ __launch_bounds__(256) void mfma_gemm_kernel(
    const int8_t* __restrict__ xq, const float* __restrict__ gam,
    const int8_t* __restrict__ wq,
    const float* __restrict__ sums, int aidx, float inv_nw,
    const float* __restrict__ resid, float* __restrict__ outf,
    _Float16* __restrict__ outh,
    int nheads, int mode, float vscale){
  __shared__ _Float16 Tr[4][64][40];   // mode-2 transpose slab (pad 40 -> 16B align)
  int lane = threadIdx.x & 63;
  int w    = threadIdx.x >> 6;
  int m0   = blockIdx.y*128 + w*32;
  int n0   = blockIdx.x*64;
  int half = lane >> 5;
  int lan5 = lane & 31;

  const int8_t* arow  = xq + (size_t)(m0 + lan5)*HIDDEN + half*16;
  const int8_t* brow0 = wq + (size_t)(n0      + lan5)*HIDDEN + half*16;
  const int8_t* brow1 = wq + (size_t)(n0 + 32 + lan5)*HIDDEN + half*16;

  int16v acc0 = {0}, acc1 = {0};
  #pragma unroll
  for (int kk=0; kk<HIDDEN; kk+=32){
    int4v a  = *(const int4v*)(arow  + kk);
    int4v b0 = *(const int4v*)(brow0 + kk);
    int4v b1 = *(const int4v*)(brow1 + kk);
    acc0 = __builtin_amdgcn_mfma_i32_32x32x32_i8(a, b0, acc0, 0, 0, 0);
    acc1 = __builtin_amdgcn_mfma_i32_32x32x32_i8(a, b1, acc1, 0, 0, 0);
  }

  float alpha = fmaxf(sums[aidx]*inv_nw, 1e-10f);
  float fr0 = 0.f, fr1 = 0.f;
  if (mode == 1){
    int d0 = (lan5) & ~1;
    int d1 = (32 + lan5) & ~1;
    fr0 = __expf(-(float)d0*(1.0f/64.0f)*13.122363377404328f);
    fr1 = __expf(-(float)d1*(1.0f/64.0f)*13.122363377404328f);
  }

  #pragma unroll
  for (int reg=0; reg<16; reg++){
    int ml = (reg&3) + 8*(reg>>2) + 4*half;   // local row 0..31
    int m = m0 + ml;
    float sc = alpha*gam[m]*(1.0f/127.0f);
    float v0 = (float)acc0[reg]*sc;
    float v1 = (float)acc1[reg]*sc;
    if (mode == 0){
      size_t ofs = (size_t)m*HIDDEN;
      outf[ofs + n0 + lan5]      = v0 + resid[ofs + n0 + lan5];
      outf[ofs + n0 + 32 + lan5] = v1 + resid[ofs + n0 + 32 + lan5];
    } else if (mode == 1){
      int b = m >> 9, l = m & 511;
      int head = n0 >> 6;
      float p0 = __shfl_xor(v0, 1);
      float p1 = __shfl_xor(v1, 1);
      float sn0, cs0, sn1, cs1;
      __sincosf((float)l*fr0, &sn0, &cs0);
      __sincosf((float)l*fr1, &sn1, &cs1);
      if (lane & 1){ v0 = v0*cs0 + p0*sn0;  v1 = v1*cs1 + p1*sn1; }
      else         { v0 = v0*cs0 - p0*sn0;  v1 = v1*cs1 - p1*sn1; }
      _Float16* dst = outh + ((((size_t)b*nheads + head)*LSEQ + l)<<6);
      dst[lan5]      = (_Float16)(v0*vscale);
      dst[32 + lan5] = (_Float16)(v1*vscale);
    } else {
      Tr[w][lan5][ml]      = (_Float16)v0;
      Tr[w][32 + lan5][ml] = (_Float16)v1;
    }
  }
  if (mode == 2){
    // wave-local: lane d reads its 32-l row, stores 64B contiguous to global
    int b = m0 >> 9, l0 = m0 & 511;
    int head = n0 >> 6;
    f16x8 r0 = *(const f16x8*)&Tr[w][lane][0];
    f16x8 r1 = *(const f16x8*)&Tr[w][lane][8];
    f16x8 r2 = *(const f16x8*)&Tr[w][lane][16];
    f16x8 r3 = *(const f16x8*)&Tr[w][lane][24];
    _Float16* dst = outh + (((size_t)b*nheads + head)*HDIM + lane)*LSEQ + l0;
    ((f16x8*)dst)[0] = r0;
    ((f16x8*)dst)[1] = r1;
    ((f16x8*)dst)[2] = r2;
    ((f16x8*)dst)[3] = r3;
  }
}

// ---------------------------------------------------------------------------
// Flash attention v3: double-buffered K/V LDS tiles -> ONE barrier per K-tile.
// Block = 256 (4 waves) owns (b, h, 64 q-rows); wave owns 16 q-rows.
// XOR-swizzled 16B-chunk layout, conflict-free. Output written f16.
__device__ __forceinline__ int kv_addr(int row, int chunk){  // in halves
  return (row<<6) + (((chunk ^ (row&7)))<<3);
}

__global__ __launch_bounds__(256,2) void attn_mfma_kernel(
    const _Float16* __restrict__ q, const _Float16* __restrict__ k,
    const _Float16* __restrict__ vt, _Float16* __restrict__ o){
  __shared__ _Float16 Ks[2][64*64];
  __shared__ _Float16 Vs[2][64*64];
  __shared__ _Float16 Ps[4][16][72];
  int tid  = threadIdx.x;
  int wv   = tid >> 6, lane = tid & 63;
  int quad = lane >> 4, c = lane & 15;
  int qt = blockIdx.x, h = blockIdx.y, b = blockIdx.z;
  int hk = h / GROUPS;
  int qrow0 = (qt<<6) + (wv<<4);

  const _Float16* qb = q + ((size_t)((b*NQH+h)*LSEQ) + qrow0 + c)*HDIM + quad*8;
  f16x8 qf0 = *(const f16x8*)qb;
  f16x8 qf1 = *(const f16x8*)(qb + 32);

  const _Float16* kbase = k  + (size_t)((b*NKVH+hk)*LSEQ)*HDIM;  // [l][d]
  const _Float16* vbase = vt + (size_t)((b*NKVH+hk)*HDIM)*LSEQ;  // [d][l]

  int srow = tid >> 3, schunk = tid & 7;
  const _Float16* kg0 = kbase + (size_t)srow*HDIM      + schunk*8;
  const _Float16* kg1 = kbase + (size_t)(srow+32)*HDIM + schunk*8;
  const _Float16* vg0 = vbase + (size_t)srow*LSEQ      + schunk*8;
  const _Float16* vg1 = vbase + (size_t)(srow+32)*LSEQ + schunk*8;
  int ka0 = kv_addr(srow,    schunk);
  int ka1 = kv_addr(srow+32, schunk);

  // stage tile 0 into buffer 0 (no barrier yet; top-of-loop barrier covers it)
  {
    f16x8 a = *(const f16x8*)kg0;
    f16x8 b2 = *(const f16x8*)kg1;
    f16x8 cc = *(const f16x8*)vg0;
    f16x8 d = *(const f16x8*)vg1;
    *(f16x8*)&Ks[0][ka0] = a;
    *(f16x8*)&Ks[0][ka1] = b2;
    *(f16x8*)&Vs[0][ka0] = cc;
    *(f16x8*)&Vs[0][ka1] = d;
  }

  f32x4 Oacc[4] = {{0,0,0,0},{0,0,0,0},{0,0,0,0},{0,0,0,0}};
  float m_i[4] = {-INFINITY,-INFINITY,-INFINITY,-INFINITY};
  float l_i[4] = {0.f,0.f,0.f,0.f};
  f16x8 pk0, pk1, pv0, pv1;

  for (int kt=0; kt<8; kt++){
    __syncthreads();                 // buf[kt&1] ready; buf[1-kt&1] free
    int cur = kt & 1, nxt = cur ^ 1;
    if (kt < 7){
      pk0 = *(const f16x8*)(kg0 + (size_t)(kt+1)*64*HDIM);
      pk1 = *(const f16x8*)(kg1 + (size_t)(kt+1)*64*HDIM);
      pv0 = *(const f16x8*)(vg0 + (kt+1)*64);
      pv1 = *(const f16x8*)(vg1 + (kt+1)*64);
    }
    // S = Q K^T
    f32x4 S[4];
    #pragma unroll
    for (int nt=0; nt<4; nt++){
      int row = (nt<<4) + c;
      f16x8 kf0 = *(const f16x8*)&Ks[cur][kv_addr(row, quad)];
      f16x8 kf1 = *(const f16x8*)&Ks[cur][kv_addr(row, quad+4)];
      f32x4 s = {0,0,0,0};
      s = __builtin_amdgcn_mfma_f32_16x16x32_f16(qf0, kf0, s, 0,0,0);
      s = __builtin_amdgcn_mfma_f32_16x16x32_f16(qf1, kf1, s, 0,0,0);
      S[nt] = s;
    }
    // online softmax
    #pragma unroll
    for (int r=0;r<4;r++){
      float mx = fmaxf(fmaxf(S[0][r],S[1][r]), fmaxf(S[2][r],S[3][r]));
      mx = fmaxf(mx, __shfl_xor(mx,1));
      mx = fmaxf(mx, __shfl_xor(mx,2));
      mx = fmaxf(mx, __shfl_xor(mx,4));
      mx = fmaxf(mx, __shfl_xor(mx,8));
      float mnew = fmaxf(m_i[r], mx);
      float af = __expf(m_i[r] - mnew);
      m_i[r] = mnew;
      float ps = 0.f;
      #pragma unroll
      for (int nt=0;nt<4;nt++){
        float p = __expf(S[nt][r] - mnew);
        ps += p;
        Ps[wv][(quad<<2)+r][(nt<<4)+c] = (_Float16)p;
      }
      ps += __shfl_xor(ps,1);
      ps += __shfl_xor(ps,2);
      ps += __shfl_xor(ps,4);
      ps += __shfl_xor(ps,8);
      l_i[r] = l_i[r]*af + ps;
      Oacc[0][r]*=af; Oacc[1][r]*=af; Oacc[2][r]*=af; Oacc[3][r]*=af;
    }
    // P: C-layout -> A-layout (wave-local slab)
    f16x8 pf0 = *(const f16x8*)&Ps[wv][c][quad*8];
    f16x8 pf1 = *(const f16x8*)&Ps[wv][c][quad*8 + 32];
    #pragma unroll
    for (int nt=0;nt<4;nt++){
      int row = (nt<<4) + c;   // d index
      f16x8 vf0 = *(const f16x8*)&Vs[cur][kv_addr(row, quad)];
      f16x8 vf1 = *(const f16x8*)&Vs[cur][kv_addr(row, quad+4)];
      Oacc[nt] = __builtin_amdgcn_mfma_f32_16x16x32_f16(pf0, vf0, Oacc[nt], 0,0,0);
      Oacc[nt] = __builtin_amdgcn_mfma_f32_16x16x32_f16(pf1, vf1, Oacc[nt], 0,0,0);
    }
    if (kt < 7){
      *(f16x8*)&Ks[nxt][ka0] = pk0;
      *(f16x8*)&Ks[nxt][ka1] = pk1;
      *(f16x8*)&Vs[nxt][ka0] = pv0;
      *(f16x8*)&Vs[nxt][ka1] = pv1;
    }
  }
  #pragma unroll
  for (int r=0;r<4;r++){
    float invl = 1.0f/l_i[r];
    int m = (b<<9) + qrow0 + (quad<<2) + r;
    _Float16* dst = o + (size_t)m*HIDDEN + (h<<6);
    #pragma unroll
    for (int nt=0;nt<4;nt++) dst[(nt<<4)+c] = (_Float16)(Oacc[nt][r]*invl);
  }
}

// ---------------------------------------------------------------------------
extern "C" void kernel_launch(void* const* d_in, const int* in_sizes, int n_in,
                              void* d_out, int out_size, void* d_ws, size_t ws_size,
                              hipStream_t stream){
  (void)in_sizes; (void)n_in; (void)out_size; (void)ws_size;
  const float* x  = (const float*)d_in[0];
  const float* nw = (const float*)d_in[1];
  const float* qw = (const float*)d_in[2];
  const float* qg = (const float*)d_in[3];
  const float* kw = (const float*)d_in[4];
  const float* kg = (const float*)d_in[5];
  const float* vw = (const float*)d_in[6];
  const float* vg = (const float*)d_in[7];
  const float* ow = (const float*)d_in[8];
  const float* og = (const float*)d_in[9];
  float* out = (float*)d_out;

  char* base = (char*)d_ws;
  size_t off = 0;
  auto alloc = [&](size_t nbytes)->void*{
    off = (off + 255) & ~(size_t)255;
    void* p = base + off;
    off += nbytes;
    return p;
  };
  float*  sums = (float*) alloc(4*sizeof(float));
  int8_t* wq_q = (int8_t*)alloc(640*640);
  int8_t* wq_k = (int8_t*)alloc(128*640);
  int8_t* wq_v = (int8_t*)alloc(128*640);
  int8_t* wq_o = (int8_t*)alloc(640*640);
  int8_t* xq_q = (int8_t*)alloc((size_t)NTOK*HIDDEN);
  int8_t* xq_k = (int8_t*)alloc((size_t)NTOK*HIDDEN);
  int8_t* xq_v = (int8_t*)alloc((size_t)NTOK*HIDDEN);
  int8_t* xq_o = (int8_t*)alloc((size_t)NTOK*HIDDEN);
  float*  g_q  = (float*) alloc((size_t)NTOK*4);
  float*  g_k  = (float*) alloc((size_t)NTOK*4);
  float*  g_v  = (float*) alloc((size_t)NTOK*4);
  float*  g_o  = (float*) alloc((size_t)NTOK*4);
  _Float16* qbuf = (_Float16*)alloc((size_t)BATCH*NQH *LSEQ*HDIM*2);
  _Float16* kbuf = (_Float16*)alloc((size_t)BATCH*NKVH*LSEQ*HDIM*2);
  _Float16* vbuf = (_Float16*)alloc((size_t)BATCH*NKVH*LSEQ*HDIM*2);
  _Float16* abuf = (_Float16*)alloc((size_t)NTOK*HIDDEN*2);

  (void)hipMemsetAsync(sums, 0, 4*sizeof(float), stream);
  absum4_kernel<<<dim3(64,4),256,0,stream>>>(qw, kw, vw, ow, sums);
  wquant4_kernel<<<dim3(1600,4),256,0,stream>>>(qw, kw, vw, ow, wq_q, wq_k, wq_v, wq_o, sums);

  token_prep_kernel<<<NTOK/4,256,0,stream>>>(x, nw, qg, kg, vg, xq_q, xq_k, xq_v, g_q, g_k, g_v);

  mfma_gemm_kernel<<<dim3(10,128),256,0,stream>>>(xq_q, g_q, wq_q, sums, 0, 1.0f/(640.f*640.f), nullptr, nullptr, qbuf, NQH, 1, 0.125f);
  mfma_gemm_kernel<<<dim3(2,128),256,0,stream>>>(xq_k, g_k, wq_k, sums, 1, 1.0f/(128.f*640.f), nullptr, nullptr, kbuf, NKVH, 1, 1.0f);
  mfma_gemm_kernel<<<dim3(2,128),256,0,stream>>>(xq_v, g_v, wq_v, sums, 2, 1.0f/(128.f*640.f), nullptr, nullptr, vbuf, NKVH, 2, 1.0f);

  attn_mfma_kernel<<<dim3(8,NQH,BATCH),256,0,stream>>>(qbuf, kbuf, vbuf, abuf);

  o_prep_kernel<<<NTOK/4,256,0,stream>>>(abuf, og, xq_o, g_o);
  mfma_gemm_kernel<<<dim3(10,128),256,0,stream>>>(xq_o, g_o, wq_o, sums, 3, 1.0f/(640.f*640.f), x, out, nullptr, 0, 0, 1.0f);
}

// Round 7
// 266.334 us; speedup vs baseline: 9.8432x; 1.2019x over previous
//
#include <hip/hip_runtime.h>
#include <math.h>
#include <stdint.h>

#define HIDDEN 640
#define NTOK   16384   // 32*512
#define LSEQ   512
#define BATCH  32
#define NQH    10
#define NKVH   2
#define HDIM   64
#define GROUPS 5

typedef int      int4v  __attribute__((ext_vector_type(4)));
typedef int      int16v __attribute__((ext_vector_type(16)));
typedef _Float16 f16x8  __attribute__((ext_vector_type(8)));
typedef _Float16 f16x2  __attribute__((ext_vector_type(2)));
typedef float    f32x4  __attribute__((ext_vector_type(4)));

// ---------------------------------------------------------------------------
__device__ __forceinline__ float wred_sum(float v){
  #pragma unroll
  for (int m=1;m<64;m<<=1) v += __shfl_xor(v,m);
  return v;
}
__device__ __forceinline__ float wred_max(float v){
  #pragma unroll
  for (int m=1;m<64;m<<=1) v = fmaxf(v,__shfl_xor(v,m));
  return v;
}
__device__ __forceinline__ f16x2 pkmax(f16x2 a, f16x2 b){
  f16x2 r;
  r.x = (a.x > b.x) ? a.x : b.x;
  r.y = (a.y > b.y) ? a.y : b.y;
  return r;
}
__device__ __forceinline__ f16x2 shflx(f16x2 v, int m){
  int t = __builtin_bit_cast(int, v);
  t = __shfl_xor(t, m);
  return __builtin_bit_cast(f16x2, t);
}

// ---------------------------------------------------------------------------
__global__ __launch_bounds__(256) void absum4_kernel(
    const float* __restrict__ w0, const float* __restrict__ w1,
    const float* __restrict__ w2, const float* __restrict__ w3,
    float* __restrict__ sums){
  const float* w; int n;
  switch(blockIdx.y){
    case 0:  w=w0; n=640*640; break;
    case 1:  w=w1; n=128*640; break;
    case 2:  w=w2; n=128*640; break;
    default: w=w3; n=640*640; break;
  }
  __shared__ float red[256];
  int tid = threadIdx.x;
  float s = 0.f;
  for (int i = blockIdx.x*256 + tid; i < n; i += gridDim.x*256) s += fabsf(w[i]);
  red[tid] = s; __syncthreads();
  for (int off=128; off>0; off>>=1){ if (tid<off) red[tid]+=red[tid+off]; __syncthreads(); }
  if (tid==0) atomicAdd(&sums[blockIdx.y], red[0]);
}

// ternarize + write B in MFMA-fragment layout:
// flat = ((n>>5)*20 + (k>>5))*1024 + (((k>>4)&1)*32 + (n&31))*16 + (k&15)
// so a wave's B-frag load at (nblk,kblk) is lane-linear (coalesced dwordx4).
__global__ __launch_bounds__(256) void wquant4_kernel(
    const float* __restrict__ w0, const float* __restrict__ w1,
    const float* __restrict__ w2, const float* __restrict__ w3,
    int8_t* __restrict__ o0, int8_t* __restrict__ o1,
    int8_t* __restrict__ o2, int8_t* __restrict__ o3,
    const float* __restrict__ sums){
  const float* w; int8_t* o; int n;
  switch(blockIdx.y){
    case 0:  w=w0; o=o0; n=640*640; break;
    case 1:  w=w1; o=o1; n=128*640; break;
    case 2:  w=w2; o=o2; n=128*640; break;
    default: w=w3; o=o3; n=640*640; break;
  }
  float alpha = fmaxf(sums[blockIdx.y]/(float)n, 1e-10f);
  float inva  = 1.0f/alpha;
  int i = blockIdx.x*256 + threadIdx.x;
  if (i < n){
    float t = rintf(w[i]*inva);            // round-half-even matches jnp.round
    t = fminf(1.f, fmaxf(-1.f, t));
    int nr = i/640;
    int kc = i - nr*640;
    int flat = (((nr>>5)*20 + (kc>>5))<<10) + (((((kc>>4)&1)<<5) | (nr&31))<<4) + (kc&15);
    o[flat] = (int8_t)t;
  }
}

// ---------------------------------------------------------------------------
// wave-per-token prep (register-resident, shuffle reductions)
__global__ __launch_bounds__(256) void token_prep_kernel(
    const float* __restrict__ x, const float* __restrict__ nw,
    const float* __restrict__ qg, const float* __restrict__ kg, const float* __restrict__ vg,
    int8_t* __restrict__ xqq, int8_t* __restrict__ xqk, int8_t* __restrict__ xqv,
    float* __restrict__ gq, float* __restrict__ gk, float* __restrict__ gv){
  int lane = threadIdx.x & 63;
  int m = blockIdx.x*4 + (threadIdx.x>>6);
  const float* xr = x + (size_t)m*HIDDEN;
  float xv[10], h[10];
  float ss = 0.f;
  #pragma unroll
  for (int j=0;j<10;j++){ float t = xr[lane + 64*j]; xv[j]=t; ss += t*t; }
  float inv1 = 1.0f/sqrtf(wred_sum(ss)*(1.0f/HIDDEN) + 1e-6f);
  float ss2 = 0.f;
  #pragma unroll
  for (int j=0;j<10;j++){ float t = xv[j]*inv1*nw[lane+64*j]; h[j]=t; ss2 += t*t; }
  float inv2 = 1.0f/sqrtf(wred_sum(ss2)*(1.0f/HIDDEN) + 1e-6f);

  const float* gs[3] = {qg, kg, vg};
  int8_t* outs[3] = {xqq, xqk, xqv};
  float* gams[3] = {gq, gk, gv};
  #pragma unroll
  for (int s=0;s<3;s++){
    const float* g = gs[s];
    float t[10], amax = 0.f;
    #pragma unroll
    for (int j=0;j<10;j++){ float v = h[j]*inv2*g[lane+64*j]; t[j]=v; amax = fmaxf(amax, fabsf(v)); }
    float gamma = fmaxf(wred_max(amax), 1e-10f);
    float sc = 127.0f/gamma;
    int8_t* dst = outs[s] + (size_t)m*HIDDEN;
    #pragma unroll
    for (int j=0;j<10;j++){
      float v = rintf(t[j]*sc);
      v = fminf(127.f, fmaxf(-128.f, v));
      dst[lane+64*j] = (int8_t)v;
    }
    if (lane==0) gams[s][m] = gamma;
  }
}

__global__ __launch_bounds__(256) void o_prep_kernel(const _Float16* __restrict__ ao,
    const float* __restrict__ og, int8_t* __restrict__ xqo, float* __restrict__ go){
  int lane = threadIdx.x & 63;
  int m = blockIdx.x*4 + (threadIdx.x>>6);
  const _Float16* xr = ao + (size_t)m*HIDDEN;
  float xv[10];
  float ss = 0.f;
  #pragma unroll
  for (int j=0;j<10;j++){ float t = (float)xr[lane + 64*j]; xv[j]=t; ss += t*t; }
  float inv = 1.0f/sqrtf(wred_sum(ss)*(1.0f/HIDDEN) + 1e-6f);
  float t[10], amax = 0.f;
  #pragma unroll
  for (int j=0;j<10;j++){ float v = xv[j]*inv*og[lane+64*j]; t[j]=v; amax = fmaxf(amax, fabsf(v)); }
  float gamma = fmaxf(wred_max(amax), 1e-10f);
  float sc = 127.0f/gamma;
  int8_t* dst = xqo + (size_t)m*HIDDEN;
  #pragma unroll
  for (int j=0;j<10;j++){
    float v = rintf(t[j]*sc);
    v = fminf(127.f, fmaxf(-128.f, v));
    dst[lane+64*j] = (int8_t)v;
  }
  if (lane==0) go[m] = gamma;
}

// ---------------------------------------------------------------------------
// i8 MFMA GEMM core: A row-major scattered, B in fragment layout (coalesced).
__device__ __forceinline__ void gemm_core(
    const int8_t* __restrict__ xq, const int8_t* __restrict__ wqf,
    int m0, int n0, int lane, int16v& acc0, int16v& acc1){
  int half = lane >> 5, lan5 = lane & 31;
  const int8_t* arow = xq + (size_t)(m0 + lan5)*HIDDEN + half*16;
  const int8_t* b0 = wqf + (((size_t)(n0>>5)    *20)<<10) + (lane<<4);
  const int8_t* b1 = wqf + (((size_t)((n0>>5)+1)*20)<<10) + (lane<<4);
  #pragma unroll
  for (int kb=0; kb<20; kb++){
    int4v a  = *(const int4v*)(arow + kb*32);
    int4v v0 = *(const int4v*)(b0 + (kb<<10));
    int4v v1 = *(const int4v*)(b1 + (kb<<10));
    acc0 = __builtin_amdgcn_mfma_i32_32x32x32_i8(a, v0, acc0, 0, 0, 0);
    acc1 = __builtin_amdgcn_mfma_i32_32x32x32_i8(a, v1, acc1, 0, 0, 0);
  }
}

// Merged QKV projection: grid (14, 128). bx<10 -> Q (rope, x0.125),
// bx in {10,11} -> K (rope), bx in {12,13} -> V (transposed store).
__global__ __launch_bounds__(256) void qkv_gemm_kernel(
    const int8_t* __restrict__ xq_q, const float* __restrict__ g_q, const int8_t* __restrict__ wq_q,
    const int8_t* __restrict__ xq_k, const float* __restrict__ g_k, const int8_t* __restrict__ wq_k,
    const int8_t* __restrict__ xq_v, const float* __restrict__ g_v, const int8_t* __restrict__ wq_v,
    const float* __restrict__ sums,
    _Float16* __restrict__ qbuf, _Float16* __restrict__ kbuf, _Float16* __restrict__ vbuf){
  __shared__ _Float16 Tr[4][64][40];
  int bx = blockIdx.x;
  const int8_t *xq, *wq; const float* gam; _Float16* outh;
  int n0, aidx, nheads, mode; float inv_nw, vscale;
  if (bx < 10){ xq=xq_q; wq=wq_q; gam=g_q; outh=qbuf; n0=bx*64;      aidx=0; inv_nw=1.0f/409600.f; nheads=NQH;  mode=1; vscale=0.125f; }
  else if (bx < 12){ xq=xq_k; wq=wq_k; gam=g_k; outh=kbuf; n0=(bx-10)*64; aidx=1; inv_nw=1.0f/81920.f; nheads=NKVH; mode=1; vscale=1.0f; }
  else { xq=xq_v; wq=wq_v; gam=g_v; outh=vbuf; n0=(bx-12)*64; aidx=2; inv_nw=1.0f/81920.f; nheads=NKVH; mode=2; vscale=1.0f; }

  int lane = threadIdx.x & 63;
  int w    = threadIdx.x >> 6;
  int m0   = blockIdx.y*128 + w*32;
  int half = lane >> 5, lan5 = lane & 31;

  int16v acc0 = {0}, acc1 = {0};
  gemm_core(xq, wq, m0, n0, lane, acc0, acc1);

  float alpha = fmaxf(sums[aidx]*inv_nw, 1e-10f);
  float fr0 = 0.f, fr1 = 0.f;
  if (mode == 1){
    int d0 = (lan5) & ~1;
    int d1 = (32 + lan5) & ~1;
    fr0 = __expf(-(float)d0*(1.0f/64.0f)*13.122363377404328f);
    fr1 = __expf(-(float)d1*(1.0f/64.0f)*13.122363377404328f);
  }

  #pragma unroll
  for (int reg=0; reg<16; reg++){
    int ml = (reg&3) + 8*(reg>>2) + 4*half;
    int m = m0 + ml;
    float sc = alpha*gam[m]*(1.0f/127.0f);
    float v0 = (float)acc0[reg]*sc;
    float v1 = (float)acc1[reg]*sc;
    if (mode == 1){
      int b = m >> 9, l = m & 511;
      int head = n0 >> 6;
      float p0 = __shfl_xor(v0, 1);
      float p1 = __shfl_xor(v1, 1);
      float sn0, cs0, sn1, cs1;
      __sincosf((float)l*fr0, &sn0, &cs0);
      __sincosf((float)l*fr1, &sn1, &cs1);
      if (lane & 1){ v0 = v0*cs0 + p0*sn0;  v1 = v1*cs1 + p1*sn1; }
      else         { v0 = v0*cs0 - p0*sn0;  v1 = v1*cs1 - p1*sn1; }
      _Float16* dst = outh + ((((size_t)b*nheads + head)*LSEQ + l)<<6);
      dst[lan5]      = (_Float16)(v0*vscale);
      dst[32 + lan5] = (_Float16)(v1*vscale);
    } else {
      Tr[w][lan5][ml]      = (_Float16)v0;
      Tr[w][32 + lan5][ml] = (_Float16)v1;
    }
  }
  if (mode == 2){
    int b = m0 >> 9, l0 = m0 & 511;
    int head = n0 >> 6;
    f16x8 r0 = *(const f16x8*)&Tr[w][lane][0];
    f16x8 r1 = *(const f16x8*)&Tr[w][lane][8];
    f16x8 r2 = *(const f16x8*)&Tr[w][lane][16];
    f16x8 r3 = *(const f16x8*)&Tr[w][lane][24];
    _Float16* dst = outh + (((size_t)b*nheads + head)*HDIM + lane)*LSEQ + l0;
    ((f16x8*)dst)[0] = r0;
    ((f16x8*)dst)[1] = r1;
    ((f16x8*)dst)[2] = r2;
    ((f16x8*)dst)[3] = r3;
  }
}

// O projection + residual (fp32 out)
__global__ __launch_bounds__(256) void out_gemm_kernel(
    const int8_t* __restrict__ xq, const float* __restrict__ gam,
    const int8_t* __restrict__ wq, const float* __restrict__ sums,
    const float* __restrict__ resid, float* __restrict__ outf){
  int lane = threadIdx.x & 63;
  int w    = threadIdx.x >> 6;
  int m0   = blockIdx.y*128 + w*32;
  int n0   = blockIdx.x*64;
  int half = lane >> 5, lan5 = lane & 31;

  int16v acc0 = {0}, acc1 = {0};
  gemm_core(xq, wq, m0, n0, lane, acc0, acc1);

  float alpha = fmaxf(sums[3]*(1.0f/409600.f), 1e-10f);
  #pragma unroll
  for (int reg=0; reg<16; reg++){
    int m = m0 + (reg&3) + 8*(reg>>2) + 4*half;
    float sc = alpha*gam[m]*(1.0f/127.0f);
    size_t ofs = (size_t)m*HIDDEN;
    outf[ofs + n0 + lan5]      = (float)acc0[reg]*sc + resid[ofs + n0 + lan5];
    outf[ofs + n0 + 32 + lan5] = (float)acc1[reg]*sc + resid[ofs + n0 + 32 + lan5];
  }
}

// ---------------------------------------------------------------------------
// Flash attention v4: 32 q-rows per wave (two 16-row groups sharing K/V
// B-fragments), packed-f16 shuffle reductions, double-buffered K/V staging.
// Block = 256 thr (4 waves) owns (b, h, 128 q-rows); grid (4, NQH, BATCH).
__device__ __forceinline__ int kv_addr(int row, int chunk){  // in halves
  return (row<<6) + (((chunk ^ (row&7)))<<3);
}

__device__ __forceinline__ void softmax_update(
    f32x4* S, float* m_i, float* l_i, f32x4* O,
    _Float16 (*PsRow)[72], int quad, int c){
  float mxr[4], psr[4];
  #pragma unroll
  for (int r=0;r<4;r++)
    mxr[r] = fmaxf(fmaxf(S[0][r],S[1][r]), fmaxf(S[2][r],S[3][r]));
  f16x2 a01 = {(_Float16)mxr[0], (_Float16)mxr[1]};
  f16x2 a23 = {(_Float16)mxr[2], (_Float16)mxr[3]};
  #pragma unroll
  for (int mm=1; mm<16; mm<<=1){
    a01 = pkmax(a01, shflx(a01, mm));
    a23 = pkmax(a23, shflx(a23, mm));
  }
  float mn[4] = {(float)a01.x, (float)a01.y, (float)a23.x, (float)a23.y};
  #pragma unroll
  for (int r=0;r<4;r++){
    float mnew = fmaxf(m_i[r], mn[r]);
    float af = __expf(m_i[r] - mnew);
    m_i[r] = mnew;
    float ps = 0.f;
    #pragma unroll
    for (int nt=0;nt<4;nt++){
      float p = __expf(S[nt][r] - mnew);
      ps += p;
      PsRow[(quad<<2)+r][(nt<<4)+c] = (_Float16)p;
    }
    psr[r] = ps;
    l_i[r] *= af;
    O[0][r]*=af; O[1][r]*=af; O[2][r]*=af; O[3][r]*=af;
  }
  f16x2 s01 = {(_Float16)psr[0], (_Float16)psr[1]};
  f16x2 s23 = {(_Float16)psr[2], (_Float16)psr[3]};
  #pragma unroll
  for (int mm=1; mm<16; mm<<=1){
    s01 = s01 + shflx(s01, mm);
    s23 = s23 + shflx(s23, mm);
  }
  l_i[0] += (float)s01.x; l_i[1] += (float)s01.y;
  l_i[2] += (float)s23.x; l_i[3] += (float)s23.y;
}

__global__ __launch_bounds__(256,2) void attn_mfma_kernel(
    const _Float16* __restrict__ q, const _Float16* __restrict__ k,
    const _Float16* __restrict__ vt, _Float16* __restrict__ o){
  __shared__ _Float16 Ks[2][64*64];
  __shared__ _Float16 Vs[2][64*64];
  __shared__ _Float16 Ps[4][32][72];
  int tid  = threadIdx.x;
  int wv   = tid >> 6, lane = tid & 63;
  int quad = lane >> 4, c = lane & 15;
  int h = blockIdx.y, b = blockIdx.z;
  int hk = h / GROUPS;
  int qrow0 = blockIdx.x*128 + wv*32;

  const _Float16* qb = q + ((size_t)((b*NQH+h)*LSEQ) + qrow0 + c)*HDIM + quad*8;
  f16x8 qa0 = *(const f16x8*)qb;                    // group0 rows qrow0+c
  f16x8 qa1 = *(const f16x8*)(qb + 32);
  f16x8 qb0 = *(const f16x8*)(qb + 16*HDIM);        // group1 rows +16
  f16x8 qb1 = *(const f16x8*)(qb + 16*HDIM + 32);

  const _Float16* kbase = k  + (size_t)((b*NKVH+hk)*LSEQ)*HDIM;  // [l][d]
  const _Float16* vbase = vt + (size_t)((b*NKVH+hk)*HDIM)*LSEQ;  // [d][l]

  int srow = tid >> 3, schunk = tid & 7;
  const _Float16* kg0 = kbase + (size_t)srow*HDIM      + schunk*8;
  const _Float16* kg1 = kbase + (size_t)(srow+32)*HDIM + schunk*8;
  const _Float16* vg0 = vbase + (size_t)srow*LSEQ      + schunk*8;
  const _Float16* vg1 = vbase + (size_t)(srow+32)*LSEQ + schunk*8;
  int ka0 = kv_addr(srow,    schunk);
  int ka1 = kv_addr(srow+32, schunk);

  {
    f16x8 t0 = *(const f16x8*)kg0;
    f16x8 t1 = *(const f16x8*)kg1;
    f16x8 t2 = *(const f16x8*)vg0;
    f16x8 t3 = *(const f16x8*)vg1;
    *(f16x8*)&Ks[0][ka0] = t0;
    *(f16x8*)&Ks[0][ka1] = t1;
    *(f16x8*)&Vs[0][ka0] = t2;
    *(f16x8*)&Vs[0][ka1] = t3;
  }

  f32x4 O0[4] = {{0,0,0,0},{0,0,0,0},{0,0,0,0},{0,0,0,0}};
  f32x4 O1[4] = {{0,0,0,0},{0,0,0,0},{0,0,0,0},{0,0,0,0}};
  float m0_[4] = {-INFINITY,-INFINITY,-INFINITY,-INFINITY};
  float m1_[4] = {-INFINITY,-INFINITY,-INFINITY,-INFINITY};
  float l0_[4] = {0,0,0,0}, l1_[4] = {0,0,0,0};
  f16x8 pk0, pk1, pv0, pv1;

  for (int kt=0; kt<8; kt++){
    __syncthreads();
    int cur = kt & 1, nxt = cur ^ 1;
    if (kt < 7){
      pk0 = *(const f16x8*)(kg0 + (size_t)(kt+1)*64*HDIM);
      pk1 = *(const f16x8*)(kg1 + (size_t)(kt+1)*64*HDIM);
      pv0 = *(const f16x8*)(vg0 + (kt+1)*64);
      pv1 = *(const f16x8*)(vg1 + (kt+1)*64);
    }
    // S = Q K^T, both groups share K-frags
    f32x4 S0[4], S1[4];
    #pragma unroll
    for (int nt=0; nt<4; nt++){
      int row = (nt<<4) + c;
      f16x8 kf0 = *(const f16x8*)&Ks[cur][kv_addr(row, quad)];
      f16x8 kf1 = *(const f16x8*)&Ks[cur][kv_addr(row, quad+4)];
      f32x4 s = {0,0,0,0};
      s = __builtin_amdgcn_mfma_f32_16x16x32_f16(qa0, kf0, s, 0,0,0);
      s = __builtin_amdgcn_mfma_f32_16x16x32_f16(qa1, kf1, s, 0,0,0);
      S0[nt] = s;
      f32x4 s2 = {0,0,0,0};
      s2 = __builtin_amdgcn_mfma_f32_16x16x32_f16(qb0, kf0, s2, 0,0,0);
      s2 = __builtin_amdgcn_mfma_f32_16x16x32_f16(qb1, kf1, s2, 0,0,0);
      S1[nt] = s2;
    }
    softmax_update(S0, m0_, l0_, O0, (_Float16(*)[72])&Ps[wv][0],  quad, c);
    softmax_update(S1, m1_, l1_, O1, (_Float16(*)[72])&Ps[wv][16], quad, c);
    // P fragments (A-layout) for both groups
    f16x8 p00 = *(const f16x8*)&Ps[wv][c][quad*8];
    f16x8 p01 = *(const f16x8*)&Ps[wv][c][quad*8 + 32];
    f16x8 p10 = *(const f16x8*)&Ps[wv][16+c][quad*8];
    f16x8 p11 = *(const f16x8*)&Ps[wv][16+c][quad*8 + 32];
    #pragma unroll
    for (int nt=0;nt<4;nt++){
      int row = (nt<<4) + c;   // d index
      f16x8 vf0 = *(const f16x8*)&Vs[cur][kv_addr(row, quad)];
      f16x8 vf1 = *(const f16x8*)&Vs[cur][kv_addr(row, quad+4)];
      O0[nt] = __builtin_amdgcn_mfma_f32_16x16x32_f16(p00, vf0, O0[nt], 0,0,0);
      O0[nt] = __builtin_amdgcn_mfma_f32_16x16x32_f16(p01, vf1, O0[nt], 0,0,0);
      O1[nt] = __builtin_amdgcn_mfma_f32_16x16x32_f16(p10, vf0, O1[nt], 0,0,0);
      O1[nt] = __builtin_amdgcn_mfma_f32_16x16x32_f16(p11, vf1, O1[nt], 0,0,0);
    }
    if (kt < 7){
      *(f16x8*)&Ks[nxt][ka0] = pk0;
      *(f16x8*)&Ks[nxt][ka1] = pk1;
      *(f16x8*)&Vs[nxt][ka0] = pv0;
      *(f16x8*)&Vs[nxt][ka1] = pv1;
    }
  }
  #pragma unroll
  for (int r=0;r<4;r++){
    float invl0 = 1.0f/l0_[r];
    float invl1 = 1.0f/l1_[r];
    int m0 = (b<<9) + qrow0 + (quad<<2) + r;
    _Float16* d0 = o + (size_t)m0*HIDDEN + (h<<6);
    _Float16* d1 = o + (size_t)(m0+16)*HIDDEN + (h<<6);
    #pragma unroll
    for (int nt=0;nt<4;nt++){
      d0[(nt<<4)+c] = (_Float16)(O0[nt][r]*invl0);
      d1[(nt<<4)+c] = (_Float16)(O1[nt][r]*invl1);
    }
  }
}

// ---------------------------------------------------------------------------
extern "C" void kernel_launch(void* const* d_in, const int* in_sizes, int n_in,
                              void* d_out, int out_size, void* d_ws, size_t ws_size,
                              hipStream_t stream){
  (void)in_sizes; (void)n_in; (void)out_size; (void)ws_size;
  const float* x  = (const float*)d_in[0];
  const float* nw = (const float*)d_in[1];
  const float* qw = (const float*)d_in[2];
  const float* qg = (const float*)d_in[3];
  const float* kw = (const float*)d_in[4];
  const float* kg = (const float*)d_in[5];
  const float* vw = (const float*)d_in[6];
  const float* vg = (const float*)d_in[7];
  const float* ow = (const float*)d_in[8];
  const float* og = (const float*)d_in[9];
  float* out = (float*)d_out;

  char* base = (char*)d_ws;
  size_t off = 0;
  auto alloc = [&](size_t nbytes)->void*{
    off = (off + 255) & ~(size_t)255;
    void* p = base + off;
    off += nbytes;
    return p;
  };
  float*  sums = (float*) alloc(4*sizeof(float));
  int8_t* wq_q = (int8_t*)alloc(640*640);
  int8_t* wq_k = (int8_t*)alloc(128*640);
  int8_t* wq_v = (int8_t*)alloc(128*640);
  int8_t* wq_o = (int8_t*)alloc(640*640);
  int8_t* xq_q = (int8_t*)alloc((size_t)NTOK*HIDDEN);
  int8_t* xq_k = (int8_t*)alloc((size_t)NTOK*HIDDEN);
  int8_t* xq_v = (int8_t*)alloc((size_t)NTOK*HIDDEN);
  int8_t* xq_o = (int8_t*)alloc((size_t)NTOK*HIDDEN);
  float*  g_q  = (float*) alloc((size_t)NTOK*4);
  float*  g_k  = (float*) alloc((size_t)NTOK*4);
  float*  g_v  = (float*) alloc((size_t)NTOK*4);
  float*  g_o  = (float*) alloc((size_t)NTOK*4);
  _Float16* qbuf = (_Float16*)alloc((size_t)BATCH*NQH *LSEQ*HDIM*2);
  _Float16* kbuf = (_Float16*)alloc((size_t)BATCH*NKVH*LSEQ*HDIM*2);
  _Float16* vbuf = (_Float16*)alloc((size_t)BATCH*NKVH*LSEQ*HDIM*2);
  _Float16* abuf = (_Float16*)alloc((size_t)NTOK*HIDDEN*2);

  (void)hipMemsetAsync(sums, 0, 4*sizeof(float), stream);
  absum4_kernel<<<dim3(64,4),256,0,stream>>>(qw, kw, vw, ow, sums);
  wquant4_kernel<<<dim3(1600,4),256,0,stream>>>(qw, kw, vw, ow, wq_q, wq_k, wq_v, wq_o, sums);

  token_prep_kernel<<<NTOK/4,256,0,stream>>>(x, nw, qg, kg, vg, xq_q, xq_k, xq_v, g_q, g_k, g_v);

  qkv_gemm_kernel<<<dim3(14,128),256,0,stream>>>(xq_q, g_q, wq_q,
                                                 xq_k, g_k, wq_k,
                                                 xq_v, g_v, wq_v,
                                                 sums, qbuf, kbuf, vbuf);

  attn_mfma_kernel<<<dim3(4,NQH,BATCH),256,0,stream>>>(qbuf, kbuf, vbuf, abuf);

  o_prep_kernel<<<NTOK/4,256,0,stream>>>(abuf, og, xq_o, g_o);
  out_gemm_kernel<<<dim3(10,128),256,0,stream>>>(xq_o, g_o, wq_o, sums, x, out);
}

// Round 8
// 259.013 us; speedup vs baseline: 10.1214x; 1.0283x over previous
//
#include <hip/hip_runtime.h>
#include <math.h>
#include <stdint.h>

#define HIDDEN 640
#define NTOK   16384   // 32*512
#define LSEQ   512
#define BATCH  32
#define NQH    10
#define NKVH   2
#define HDIM   64
#define GROUPS 5

typedef int      int4v  __attribute__((ext_vector_type(4)));
typedef int      int16v __attribute__((ext_vector_type(16)));
typedef _Float16 f16x8  __attribute__((ext_vector_type(8)));
typedef _Float16 f16x2  __attribute__((ext_vector_type(2)));
typedef float    f32x4  __attribute__((ext_vector_type(4)));

// ---------------------------------------------------------------------------
__device__ __forceinline__ float wred_sum(float v){
  #pragma unroll
  for (int m=1;m<64;m<<=1) v += __shfl_xor(v,m);
  return v;
}
__device__ __forceinline__ float wred_max(float v){
  #pragma unroll
  for (int m=1;m<64;m<<=1) v = fmaxf(v,__shfl_xor(v,m));
  return v;
}
__device__ __forceinline__ f16x2 pkmax(f16x2 a, f16x2 b){
  f16x2 r;
  r.x = (a.x > b.x) ? a.x : b.x;
  r.y = (a.y > b.y) ? a.y : b.y;
  return r;
}
__device__ __forceinline__ f16x2 shflx(f16x2 v, int m){
  int t = __builtin_bit_cast(int, v);
  t = __shfl_xor(t, m);
  return __builtin_bit_cast(f16x2, t);
}

// fragment-layout flat address for an MxK i8 matrix (K=640), used for both
// A (m rows) and B (n rows): lane-linear 16B per (32-row, 32-k) block.
__device__ __forceinline__ int frag_flat(int m, int k){
  return (((m>>5)*20 + (k>>5))<<10) + (((((k>>4)&1)<<5) | (m&31))<<4) + (k&15);
}

// ---------------------------------------------------------------------------
__global__ __launch_bounds__(256) void absum4_kernel(
    const float* __restrict__ w0, const float* __restrict__ w1,
    const float* __restrict__ w2, const float* __restrict__ w3,
    float* __restrict__ sums){
  const float* w; int n;
  switch(blockIdx.y){
    case 0:  w=w0; n=640*640; break;
    case 1:  w=w1; n=128*640; break;
    case 2:  w=w2; n=128*640; break;
    default: w=w3; n=640*640; break;
  }
  __shared__ float red[256];
  int tid = threadIdx.x;
  float s = 0.f;
  for (int i = blockIdx.x*256 + tid; i < n; i += gridDim.x*256) s += fabsf(w[i]);
  red[tid] = s; __syncthreads();
  for (int off=128; off>0; off>>=1){ if (tid<off) red[tid]+=red[tid+off]; __syncthreads(); }
  if (tid==0) atomicAdd(&sums[blockIdx.y], red[0]);
}

// ternarize + write B in MFMA-fragment layout (coalesced B-frag loads)
__global__ __launch_bounds__(256) void wquant4_kernel(
    const float* __restrict__ w0, const float* __restrict__ w1,
    const float* __restrict__ w2, const float* __restrict__ w3,
    int8_t* __restrict__ o0, int8_t* __restrict__ o1,
    int8_t* __restrict__ o2, int8_t* __restrict__ o3,
    const float* __restrict__ sums){
  const float* w; int8_t* o; int n;
  switch(blockIdx.y){
    case 0:  w=w0; o=o0; n=640*640; break;
    case 1:  w=w1; o=o1; n=128*640; break;
    case 2:  w=w2; o=o2; n=128*640; break;
    default: w=w3; o=o3; n=640*640; break;
  }
  float alpha = fmaxf(sums[blockIdx.y]/(float)n, 1e-10f);
  float inva  = 1.0f/alpha;
  int i = blockIdx.x*256 + threadIdx.x;
  if (i < n){
    float t = rintf(w[i]*inva);            // round-half-even matches jnp.round
    t = fminf(1.f, fmaxf(-1.f, t));
    int nr = i/640;
    int kc = i - nr*640;
    o[frag_flat(nr, kc)] = (int8_t)t;
  }
}

// ---------------------------------------------------------------------------
// wave-per-token prep; activations written in A-fragment layout.
__global__ __launch_bounds__(256) void token_prep_kernel(
    const float* __restrict__ x, const float* __restrict__ nw,
    const float* __restrict__ qg, const float* __restrict__ kg, const float* __restrict__ vg,
    int8_t* __restrict__ xqq, int8_t* __restrict__ xqk, int8_t* __restrict__ xqv,
    float* __restrict__ gq, float* __restrict__ gk, float* __restrict__ gv){
  int lane = threadIdx.x & 63;
  int m = blockIdx.x*4 + (threadIdx.x>>6);
  const float* xr = x + (size_t)m*HIDDEN;
  // frag write address: base + koff + j*2048   (k = lane + 64j)
  int abase = ((m>>5)*20480) + ((m&31)<<4)
            + ((lane>>5)<<10) + (((lane>>4)&1)<<9) + (lane&15);
  float xv[10], h[10];
  float ss = 0.f;
  #pragma unroll
  for (int j=0;j<10;j++){ float t = xr[lane + 64*j]; xv[j]=t; ss += t*t; }
  float inv1 = 1.0f/sqrtf(wred_sum(ss)*(1.0f/HIDDEN) + 1e-6f);
  float ss2 = 0.f;
  #pragma unroll
  for (int j=0;j<10;j++){ float t = xv[j]*inv1*nw[lane+64*j]; h[j]=t; ss2 += t*t; }
  float inv2 = 1.0f/sqrtf(wred_sum(ss2)*(1.0f/HIDDEN) + 1e-6f);

  const float* gs[3] = {qg, kg, vg};
  int8_t* outs[3] = {xqq, xqk, xqv};
  float* gams[3] = {gq, gk, gv};
  #pragma unroll
  for (int s=0;s<3;s++){
    const float* g = gs[s];
    float t[10], amax = 0.f;
    #pragma unroll
    for (int j=0;j<10;j++){ float v = h[j]*inv2*g[lane+64*j]; t[j]=v; amax = fmaxf(amax, fabsf(v)); }
    float gamma = fmaxf(wred_max(amax), 1e-10f);
    float sc = 127.0f/gamma;
    int8_t* dst = outs[s] + abase;
    #pragma unroll
    for (int j=0;j<10;j++){
      float v = rintf(t[j]*sc);
      v = fminf(127.f, fmaxf(-128.f, v));
      dst[j*2048] = (int8_t)v;
    }
    if (lane==0) gams[s][m] = gamma;
  }
}

__global__ __launch_bounds__(256) void o_prep_kernel(const _Float16* __restrict__ ao,
    const float* __restrict__ og, int8_t* __restrict__ xqo, float* __restrict__ go){
  int lane = threadIdx.x & 63;
  int m = blockIdx.x*4 + (threadIdx.x>>6);
  const _Float16* xr = ao + (size_t)m*HIDDEN;
  int abase = ((m>>5)*20480) + ((m&31)<<4)
            + ((lane>>5)<<10) + (((lane>>4)&1)<<9) + (lane&15);
  float xv[10];
  float ss = 0.f;
  #pragma unroll
  for (int j=0;j<10;j++){ float t = (float)xr[lane + 64*j]; xv[j]=t; ss += t*t; }
  float inv = 1.0f/sqrtf(wred_sum(ss)*(1.0f/HIDDEN) + 1e-6f);
  float t[10], amax = 0.f;
  #pragma unroll
  for (int j=0;j<10;j++){ float v = xv[j]*inv*og[lane+64*j]; t[j]=v; amax = fmaxf(amax, fabsf(v)); }
  float gamma = fmaxf(wred_max(amax), 1e-10f);
  float sc = 127.0f/gamma;
  int8_t* dst = xqo + abase;
  #pragma unroll
  for (int j=0;j<10;j++){
    float v = rintf(t[j]*sc);
    v = fminf(127.f, fmaxf(-128.f, v));
    dst[j*2048] = (int8_t)v;
  }
  if (lane==0) go[m] = gamma;
}

// ---------------------------------------------------------------------------
// i8 MFMA GEMM core: BOTH A and B in fragment layout -> all loads lane-linear.
__device__ __forceinline__ void gemm_core(
    const int8_t* __restrict__ xq, const int8_t* __restrict__ wqf,
    int m0, int n0, int lane, int16v& acc0, int16v& acc1){
  const int8_t* a0 = xq  + (size_t)(m0>>5)*20480 + (lane<<4);
  const int8_t* b0 = wqf + (size_t)(n0>>5)*20480 + (lane<<4);
  const int8_t* b1 = b0 + 20480;
  #pragma unroll
  for (int kb=0; kb<20; kb++){
    int4v a  = *(const int4v*)(a0 + (kb<<10));
    int4v v0 = *(const int4v*)(b0 + (kb<<10));
    int4v v1 = *(const int4v*)(b1 + (kb<<10));
    acc0 = __builtin_amdgcn_mfma_i32_32x32x32_i8(a, v0, acc0, 0, 0, 0);
    acc1 = __builtin_amdgcn_mfma_i32_32x32x32_i8(a, v1, acc1, 0, 0, 0);
  }
}

// Merged QKV projection: grid (14, 128). bx<10 -> Q (rope, x0.125/ln2),
// bx in {10,11} -> K (rope), bx in {12,13} -> V (transposed store).
__global__ __launch_bounds__(256) void qkv_gemm_kernel(
    const int8_t* __restrict__ xq_q, const float* __restrict__ g_q, const int8_t* __restrict__ wq_q,
    const int8_t* __restrict__ xq_k, const float* __restrict__ g_k, const int8_t* __restrict__ wq_k,
    const int8_t* __restrict__ xq_v, const float* __restrict__ g_v, const int8_t* __restrict__ wq_v,
    const float* __restrict__ sums,
    _Float16* __restrict__ qbuf, _Float16* __restrict__ kbuf, _Float16* __restrict__ vbuf){
  __shared__ _Float16 Tr[4][64][40];
  int bx = blockIdx.x;
  const int8_t *xq, *wq; const float* gam; _Float16* outh;
  int n0, aidx, nheads, mode; float inv_nw, vscale;
  // Q scale folds 1/8 (attn scale) * 1/ln2 (exp2-domain softmax)
  if (bx < 10){ xq=xq_q; wq=wq_q; gam=g_q; outh=qbuf; n0=bx*64;      aidx=0; inv_nw=1.0f/409600.f; nheads=NQH;  mode=1; vscale=0.18033688011110918f; }
  else if (bx < 12){ xq=xq_k; wq=wq_k; gam=g_k; outh=kbuf; n0=(bx-10)*64; aidx=1; inv_nw=1.0f/81920.f; nheads=NKVH; mode=1; vscale=1.0f; }
  else { xq=xq_v; wq=wq_v; gam=g_v; outh=vbuf; n0=(bx-12)*64; aidx=2; inv_nw=1.0f/81920.f; nheads=NKVH; mode=2; vscale=1.0f; }

  int lane = threadIdx.x & 63;
  int w    = threadIdx.x >> 6;
  int m0   = blockIdx.y*128 + w*32;
  int half = lane >> 5, lan5 = lane & 31;

  int16v acc0 = {0}, acc1 = {0};
  gemm_core(xq, wq, m0, n0, lane, acc0, acc1);

  float alpha = fmaxf(sums[aidx]*inv_nw, 1e-10f);
  float fr0 = 0.f, fr1 = 0.f;
  if (mode == 1){
    int d0 = (lan5) & ~1;
    int d1 = (32 + lan5) & ~1;
    fr0 = __expf(-(float)d0*(1.0f/64.0f)*13.122363377404328f);
    fr1 = __expf(-(float)d1*(1.0f/64.0f)*13.122363377404328f);
  }

  #pragma unroll
  for (int reg=0; reg<16; reg++){
    int ml = (reg&3) + 8*(reg>>2) + 4*half;
    int m = m0 + ml;
    float sc = alpha*gam[m]*(1.0f/127.0f);
    float v0 = (float)acc0[reg]*sc;
    float v1 = (float)acc1[reg]*sc;
    if (mode == 1){
      int b = m >> 9, l = m & 511;
      int head = n0 >> 6;
      float p0 = __shfl_xor(v0, 1);
      float p1 = __shfl_xor(v1, 1);
      float sn0, cs0, sn1, cs1;
      __sincosf((float)l*fr0, &sn0, &cs0);
      __sincosf((float)l*fr1, &sn1, &cs1);
      if (lane & 1){ v0 = v0*cs0 + p0*sn0;  v1 = v1*cs1 + p1*sn1; }
      else         { v0 = v0*cs0 - p0*sn0;  v1 = v1*cs1 - p1*sn1; }
      _Float16* dst = outh + ((((size_t)b*nheads + head)*LSEQ + l)<<6);
      dst[lan5]      = (_Float16)(v0*vscale);
      dst[32 + lan5] = (_Float16)(v1*vscale);
    } else {
      Tr[w][lan5][ml]      = (_Float16)v0;
      Tr[w][32 + lan5][ml] = (_Float16)v1;
    }
  }
  if (mode == 2){
    int b = m0 >> 9, l0 = m0 & 511;
    int head = n0 >> 6;
    f16x8 r0 = *(const f16x8*)&Tr[w][lane][0];
    f16x8 r1 = *(const f16x8*)&Tr[w][lane][8];
    f16x8 r2 = *(const f16x8*)&Tr[w][lane][16];
    f16x8 r3 = *(const f16x8*)&Tr[w][lane][24];
    _Float16* dst = outh + (((size_t)b*nheads + head)*HDIM + lane)*LSEQ + l0;
    ((f16x8*)dst)[0] = r0;
    ((f16x8*)dst)[1] = r1;
    ((f16x8*)dst)[2] = r2;
    ((f16x8*)dst)[3] = r3;
  }
}

// O projection + residual (fp32 out)
__global__ __launch_bounds__(256) void out_gemm_kernel(
    const int8_t* __restrict__ xq, const float* __restrict__ gam,
    const int8_t* __restrict__ wq, const float* __restrict__ sums,
    const float* __restrict__ resid, float* __restrict__ outf){
  int lane = threadIdx.x & 63;
  int w    = threadIdx.x >> 6;
  int m0   = blockIdx.y*128 + w*32;
  int n0   = blockIdx.x*64;
  int half = lane >> 5, lan5 = lane & 31;

  int16v acc0 = {0}, acc1 = {0};
  gemm_core(xq, wq, m0, n0, lane, acc0, acc1);

  float alpha = fmaxf(sums[3]*(1.0f/409600.f), 1e-10f);
  #pragma unroll
  for (int reg=0; reg<16; reg++){
    int m = m0 + (reg&3) + 8*(reg>>2) + 4*half;
    float sc = alpha*gam[m]*(1.0f/127.0f);
    size_t ofs = (size_t)m*HIDDEN;
    outf[ofs + n0 + lan5]      = (float)acc0[reg]*sc + resid[ofs + n0 + lan5];
    outf[ofs + n0 + 32 + lan5] = (float)acc1[reg]*sc + resid[ofs + n0 + 32 + lan5];
  }
}

// ---------------------------------------------------------------------------
// Flash attention v5: 32 q-rows/wave, exp2-domain softmax (Q pre-scaled by
// 1/(8 ln2)), packed-f16 reductions, double-buffered K/V staging.
__device__ __forceinline__ int kv_addr(int row, int chunk){  // in halves
  return (row<<6) + (((chunk ^ (row&7)))<<3);
}

__device__ __forceinline__ void softmax_update(
    f32x4* S, float* m_i, float* l_i, f32x4* O,
    _Float16 (*PsRow)[72], int quad, int c){
  float mxr[4], psr[4];
  #pragma unroll
  for (int r=0;r<4;r++)
    mxr[r] = fmaxf(fmaxf(S[0][r],S[1][r]), fmaxf(S[2][r],S[3][r]));
  f16x2 a01 = {(_Float16)mxr[0], (_Float16)mxr[1]};
  f16x2 a23 = {(_Float16)mxr[2], (_Float16)mxr[3]};
  #pragma unroll
  for (int mm=1; mm<16; mm<<=1){
    a01 = pkmax(a01, shflx(a01, mm));
    a23 = pkmax(a23, shflx(a23, mm));
  }
  float mn[4] = {(float)a01.x, (float)a01.y, (float)a23.x, (float)a23.y};
  #pragma unroll
  for (int r=0;r<4;r++){
    float mnew = fmaxf(m_i[r], mn[r]);
    float af = exp2f(m_i[r] - mnew);
    m_i[r] = mnew;
    float ps = 0.f;
    #pragma unroll
    for (int nt=0;nt<4;nt++){
      float p = exp2f(S[nt][r] - mnew);
      ps += p;
      PsRow[(quad<<2)+r][(nt<<4)+c] = (_Float16)p;
    }
    psr[r] = ps;
    l_i[r] *= af;
    O[0][r]*=af; O[1][r]*=af; O[2][r]*=af; O[3][r]*=af;
  }
  f16x2 s01 = {(_Float16)psr[0], (_Float16)psr[1]};
  f16x2 s23 = {(_Float16)psr[2], (_Float16)psr[3]};
  #pragma unroll
  for (int mm=1; mm<16; mm<<=1){
    s01 = s01 + shflx(s01, mm);
    s23 = s23 + shflx(s23, mm);
  }
  l_i[0] += (float)s01.x; l_i[1] += (float)s01.y;
  l_i[2] += (float)s23.x; l_i[3] += (float)s23.y;
}

__global__ __launch_bounds__(256,2) void attn_mfma_kernel(
    const _Float16* __restrict__ q, const _Float16* __restrict__ k,
    const _Float16* __restrict__ vt, _Float16* __restrict__ o){
  __shared__ _Float16 Ks[2][64*64];
  __shared__ _Float16 Vs[2][64*64];
  __shared__ _Float16 Ps[4][32][72];
  int tid  = threadIdx.x;
  int wv   = tid >> 6, lane = tid & 63;
  int quad = lane >> 4, c = lane & 15;
  int h = blockIdx.y, b = blockIdx.z;
  int hk = h / GROUPS;
  int qrow0 = blockIdx.x*128 + wv*32;

  const _Float16* qb = q + ((size_t)((b*NQH+h)*LSEQ) + qrow0 + c)*HDIM + quad*8;
  f16x8 qa0 = *(const f16x8*)qb;
  f16x8 qa1 = *(const f16x8*)(qb + 32);
  f16x8 qb0 = *(const f16x8*)(qb + 16*HDIM);
  f16x8 qb1 = *(const f16x8*)(qb + 16*HDIM + 32);

  const _Float16* kbase = k  + (size_t)((b*NKVH+hk)*LSEQ)*HDIM;  // [l][d]
  const _Float16* vbase = vt + (size_t)((b*NKVH+hk)*HDIM)*LSEQ;  // [d][l]

  int srow = tid >> 3, schunk = tid & 7;
  const _Float16* kg0 = kbase + (size_t)srow*HDIM      + schunk*8;
  const _Float16* kg1 = kbase + (size_t)(srow+32)*HDIM + schunk*8;
  const _Float16* vg0 = vbase + (size_t)srow*LSEQ      + schunk*8;
  const _Float16* vg1 = vbase + (size_t)(srow+32)*LSEQ + schunk*8;
  int ka0 = kv_addr(srow,    schunk);
  int ka1 = kv_addr(srow+32, schunk);

  {
    f16x8 t0 = *(const f16x8*)kg0;
    f16x8 t1 = *(const f16x8*)kg1;
    f16x8 t2 = *(const f16x8*)vg0;
    f16x8 t3 = *(const f16x8*)vg1;
    *(f16x8*)&Ks[0][ka0] = t0;
    *(f16x8*)&Ks[0][ka1] = t1;
    *(f16x8*)&Vs[0][ka0] = t2;
    *(f16x8*)&Vs[0][ka1] = t3;
  }

  f32x4 O0[4] = {{0,0,0,0},{0,0,0,0},{0,0,0,0},{0,0,0,0}};
  f32x4 O1[4] = {{0,0,0,0},{0,0,0,0},{0,0,0,0},{0,0,0,0}};
  float m0_[4] = {-INFINITY,-INFINITY,-INFINITY,-INFINITY};
  float m1_[4] = {-INFINITY,-INFINITY,-INFINITY,-INFINITY};
  float l0_[4] = {0,0,0,0}, l1_[4] = {0,0,0,0};
  f16x8 pk0, pk1, pv0, pv1;

  for (int kt=0; kt<8; kt++){
    __syncthreads();
    int cur = kt & 1, nxt = cur ^ 1;
    if (kt < 7){
      pk0 = *(const f16x8*)(kg0 + (size_t)(kt+1)*64*HDIM);
      pk1 = *(const f16x8*)(kg1 + (size_t)(kt+1)*64*HDIM);
      pv0 = *(const f16x8*)(vg0 + (kt+1)*64);
      pv1 = *(const f16x8*)(vg1 + (kt+1)*64);
    }
    f32x4 S0[4], S1[4];
    #pragma unroll
    for (int nt=0; nt<4; nt++){
      int row = (nt<<4) + c;
      f16x8 kf0 = *(const f16x8*)&Ks[cur][kv_addr(row, quad)];
      f16x8 kf1 = *(const f16x8*)&Ks[cur][kv_addr(row, quad+4)];
      f32x4 s = {0,0,0,0};
      s = __builtin_amdgcn_mfma_f32_16x16x32_f16(qa0, kf0, s, 0,0,0);
      s = __builtin_amdgcn_mfma_f32_16x16x32_f16(qa1, kf1, s, 0,0,0);
      S0[nt] = s;
      f32x4 s2 = {0,0,0,0};
      s2 = __builtin_amdgcn_mfma_f32_16x16x32_f16(qb0, kf0, s2, 0,0,0);
      s2 = __builtin_amdgcn_mfma_f32_16x16x32_f16(qb1, kf1, s2, 0,0,0);
      S1[nt] = s2;
    }
    softmax_update(S0, m0_, l0_, O0, (_Float16(*)[72])&Ps[wv][0],  quad, c);
    softmax_update(S1, m1_, l1_, O1, (_Float16(*)[72])&Ps[wv][16], quad, c);
    f16x8 p00 = *(const f16x8*)&Ps[wv][c][quad*8];
    f16x8 p01 = *(const f16x8*)&Ps[wv][c][quad*8 + 32];
    f16x8 p10 = *(const f16x8*)&Ps[wv][16+c][quad*8];
    f16x8 p11 = *(const f16x8*)&Ps[wv][16+c][quad*8 + 32];
    #pragma unroll
    for (int nt=0;nt<4;nt++){
      int row = (nt<<4) + c;
      f16x8 vf0 = *(const f16x8*)&Vs[cur][kv_addr(row, quad)];
      f16x8 vf1 = *(const f16x8*)&Vs[cur][kv_addr(row, quad+4)];
      O0[nt] = __builtin_amdgcn_mfma_f32_16x16x32_f16(p00, vf0, O0[nt], 0,0,0);
      O0[nt] = __builtin_amdgcn_mfma_f32_16x16x32_f16(p01, vf1, O0[nt], 0,0,0);
      O1[nt] = __builtin_amdgcn_mfma_f32_16x16x32_f16(p10, vf0, O1[nt], 0,0,0);
      O1[nt] = __builtin_amdgcn_mfma_f32_16x16x32_f16(p11, vf1, O1[nt], 0,0,0);
    }
    if (kt < 7){
      *(f16x8*)&Ks[nxt][ka0] = pk0;
      *(f16x8*)&Ks[nxt][ka1] = pk1;
      *(f16x8*)&Vs[nxt][ka0] = pv0;
      *(f16x8*)&Vs[nxt][ka1] = pv1;
    }
  }
  #pragma unroll
  for (int r=0;r<4;r++){
    float invl0 = 1.0f/l0_[r];
    float invl1 = 1.0f/l1_[r];
    int m0 = (b<<9) + qrow0 + (quad<<2) + r;
    _Float16* d0 = o + (size_t)m0*HIDDEN + (h<<6);
    _Float16* d1 = o + (size_t)(m0+16)*HIDDEN + (h<<6);
    #pragma unroll
    for (int nt=0;nt<4;nt++){
      d0[(nt<<4)+c] = (_Float16)(O0[nt][r]*invl0);
      d1[(nt<<4)+c] = (_Float16)(O1[nt][r]*invl1);
    }
  }
}

// ---------------------------------------------------------------------------
extern "C" void kernel_launch(void* const* d_in, const int* in_sizes, int n_in,
                              void* d_out, int out_size, void* d_ws, size_t ws_size,
                              hipStream_t stream){
  (void)in_sizes; (void)n_in; (void)out_size; (void)ws_size;
  const float* x  = (const float*)d_in[0];
  const float* nw = (const float*)d_in[1];
  const float* qw = (const float*)d_in[2];
  const float* qg = (const float*)d_in[3];
  const float* kw = (const float*)d_in[4];
  const float* kg = (const float*)d_in[5];
  const float* vw = (const float*)d_in[6];
  const float* vg = (const float*)d_in[7];
  const float* ow = (const float*)d_in[8];
  const float* og = (const float*)d_in[9];
  float* out = (float*)d_out;

  char* base = (char*)d_ws;
  size_t off = 0;
  auto alloc = [&](size_t nbytes)->void*{
    off = (off + 255) & ~(size_t)255;
    void* p = base + off;
    off += nbytes;
    return p;
  };
  float*  sums = (float*) alloc(4*sizeof(float));
  int8_t* wq_q = (int8_t*)alloc(640*640);
  int8_t* wq_k = (int8_t*)alloc(128*640);
  int8_t* wq_v = (int8_t*)alloc(128*640);
  int8_t* wq_o = (int8_t*)alloc(640*640);
  int8_t* xq_q = (int8_t*)alloc((size_t)NTOK*HIDDEN);
  int8_t* xq_k = (int8_t*)alloc((size_t)NTOK*HIDDEN);
  int8_t* xq_v = (int8_t*)alloc((size_t)NTOK*HIDDEN);
  int8_t* xq_o = (int8_t*)alloc((size_t)NTOK*HIDDEN);
  float*  g_q  = (float*) alloc((size_t)NTOK*4);
  float*  g_k  = (float*) alloc((size_t)NTOK*4);
  float*  g_v  = (float*) alloc((size_t)NTOK*4);
  float*  g_o  = (float*) alloc((size_t)NTOK*4);
  _Float16* qbuf = (_Float16*)alloc((size_t)BATCH*NQH *LSEQ*HDIM*2);
  _Float16* kbuf = (_Float16*)alloc((size_t)BATCH*NKVH*LSEQ*HDIM*2);
  _Float16* vbuf = (_Float16*)alloc((size_t)BATCH*NKVH*LSEQ*HDIM*2);
  _Float16* abuf = (_Float16*)alloc((size_t)NTOK*HIDDEN*2);

  (void)hipMemsetAsync(sums, 0, 4*sizeof(float), stream);
  absum4_kernel<<<dim3(64,4),256,0,stream>>>(qw, kw, vw, ow, sums);
  wquant4_kernel<<<dim3(1600,4),256,0,stream>>>(qw, kw, vw, ow, wq_q, wq_k, wq_v, wq_o, sums);

  token_prep_kernel<<<NTOK/4,256,0,stream>>>(x, nw, qg, kg, vg, xq_q, xq_k, xq_v, g_q, g_k, g_v);

  qkv_gemm_kernel<<<dim3(14,128),256,0,stream>>>(xq_q, g_q, wq_q,
                                                 xq_k, g_k, wq_k,
                                                 xq_v, g_v, wq_v,
                                                 sums, qbuf, kbuf, vbuf);

  attn_mfma_kernel<<<dim3(4,NQH,BATCH),256,0,stream>>>(qbuf, kbuf, vbuf, abuf);

  o_prep_kernel<<<NTOK/4,256,0,stream>>>(abuf, og, xq_o, g_o);
  out_gemm_kernel<<<dim3(10,128),256,0,stream>>>(xq_o, g_o, wq_o, sums, x, out);
}